// Round 1
// baseline (258.164 us; speedup 1.0000x reference)
//
#include <hip/hip_runtime.h>

typedef __bf16 bf16;
typedef __bf16 bf16x4 __attribute__((ext_vector_type(4)));
typedef __bf16 bf16x8 __attribute__((ext_vector_type(8)));
typedef float  f32x4  __attribute__((ext_vector_type(4)));

#define S_LEN 2048
#define DHEAD 64
#define QB    64   // q rows per block (16 per wave x 4 waves)
#define KB    64   // kv rows per tile
#define LDK   72   // 64 + 8 bf16 pad: rows stay 16B-aligned, bank stride 4 mod 32
#define LDV   72

// Flash attention fwd: S=QK^T (bf16 MFMA, fp32 acc), online softmax, O=PV.
// Scale (1/sqrt(D))*log2(e) folded into Q preload; exp2f for exponentials.
__global__ __launch_bounds__(256, 2)
void attn_fwd(const float* __restrict__ Qg0, const float* __restrict__ Kg0,
              const float* __restrict__ Vg0, float* __restrict__ Og0) {
  __shared__ __align__(16) bf16 Kl[KB][LDK];        // K tile, row-major
  __shared__ __align__(16) bf16 Vt[DHEAD][LDV];     // V tile, transposed [d][kv]
  __shared__ __align__(16) bf16 Pl[4][16][LDK];     // per-wave P scratch

  const int tid  = threadIdx.x;
  const int wid  = tid >> 6;
  const int lane = tid & 63;
  const int l15  = lane & 15;
  const int lg   = lane >> 4;

  const int bh    = blockIdx.x >> 5;   // 0..31  (B*H)
  const int qb    = blockIdx.x & 31;   // 0..31  (S/QB)
  const int qbase = qb * QB + wid * 16;

  const size_t base = (size_t)bh * S_LEN * DHEAD;
  const float* Qg = Qg0 + base;
  const float* Kg = Kg0 + base;
  const float* Vg = Vg0 + base;
  float*       Og = Og0 + base;

  // ---- Q fragments (A-layout: row = lane&15, k = (lane>>4)*8 + j), pre-scaled
  const float qscale = 0.125f * 1.44269504088896341f;
  bf16x8 qfrag[2];
  {
    const float* qrow = Qg + (size_t)(qbase + l15) * DHEAD;
#pragma unroll
    for (int h = 0; h < 2; ++h) {
      const float* p = qrow + h * 32 + lg * 8;
      const float4 a = *(const float4*)(p);
      const float4 b = *(const float4*)(p + 4);
      bf16x8 f;
      f[0] = (bf16)(a.x * qscale); f[1] = (bf16)(a.y * qscale);
      f[2] = (bf16)(a.z * qscale); f[3] = (bf16)(a.w * qscale);
      f[4] = (bf16)(b.x * qscale); f[5] = (bf16)(b.y * qscale);
      f[6] = (bf16)(b.z * qscale); f[7] = (bf16)(b.w * qscale);
      qfrag[h] = f;
    }
  }

  // ---- online softmax state; lane's reg r tracks q-row (lg*4 + r)
  float m_r[4], l_r[4];
  f32x4 o_acc[4];
#pragma unroll
  for (int r = 0; r < 4; ++r) {
    m_r[r] = -__builtin_inff();
    l_r[r] = 0.f;
    o_acc[r] = f32x4{0.f, 0.f, 0.f, 0.f};
  }

  for (int kt = 0; kt < S_LEN / KB; ++kt) {
    __syncthreads();  // previous tile's LDS reads complete before overwrite
    // ---- stage K (row-major) and V (transposed) as bf16; 4 float4 per thread each
#pragma unroll
    for (int it = 0; it < 4; ++it) {
      const int i   = tid + it * 256;   // 0..1023
      const int row = i >> 4;           // kv row 0..63
      const int c4  = (i & 15) << 2;    // d col 0..60
      const float4 kk = *(const float4*)(Kg + (size_t)(kt * KB + row) * DHEAD + c4);
      bf16x4 kb;
      kb[0] = (bf16)kk.x; kb[1] = (bf16)kk.y; kb[2] = (bf16)kk.z; kb[3] = (bf16)kk.w;
      *(bf16x4*)&Kl[row][c4] = kb;
      const float4 vv = *(const float4*)(Vg + (size_t)(kt * KB + row) * DHEAD + c4);
      Vt[c4 + 0][row] = (bf16)vv.x;
      Vt[c4 + 1][row] = (bf16)vv.y;
      Vt[c4 + 2][row] = (bf16)vv.z;
      Vt[c4 + 3][row] = (bf16)vv.w;
    }
    __syncthreads();

    // ---- S = Q K^T : 16x64 per wave, 4 n-subtiles x 2 K-halves
    f32x4 sacc[4] = {};
#pragma unroll
    for (int ns = 0; ns < 4; ++ns) {
#pragma unroll
      for (int h = 0; h < 2; ++h) {
        const bf16x8 kf = *(const bf16x8*)&Kl[ns * 16 + l15][h * 32 + lg * 8];
        sacc[ns] = __builtin_amdgcn_mfma_f32_16x16x32_bf16(qfrag[h], kf, sacc[ns], 0, 0, 0);
      }
    }

    // ---- online softmax. C/D layout: col = lane&15, row = lg*4 + reg.
    float rmax[4];
#pragma unroll
    for (int r = 0; r < 4; ++r)
      rmax[r] = fmaxf(fmaxf(sacc[0][r], sacc[1][r]), fmaxf(sacc[2][r], sacc[3][r]));
#pragma unroll
    for (int off = 1; off < 16; off <<= 1) {
#pragma unroll
      for (int r = 0; r < 4; ++r)
        rmax[r] = fmaxf(rmax[r], __shfl_xor(rmax[r], off));
    }

    float alpha[4], rsum[4];
#pragma unroll
    for (int r = 0; r < 4; ++r) {
      const float mn = fmaxf(m_r[r], rmax[r]);
      alpha[r] = exp2f(m_r[r] - mn);   // first iter: exp2(-inf) = 0
      m_r[r]   = mn;
      rsum[r]  = 0.f;
    }
#pragma unroll
    for (int ns = 0; ns < 4; ++ns) {
#pragma unroll
      for (int r = 0; r < 4; ++r) {
        const float p = exp2f(sacc[ns][r] - m_r[r]);
        sacc[ns][r] = p;
        rsum[r] += p;
      }
    }
#pragma unroll
    for (int off = 1; off < 16; off <<= 1) {
#pragma unroll
      for (int r = 0; r < 4; ++r)
        rsum[r] += __shfl_xor(rsum[r], off);
    }
#pragma unroll
    for (int r = 0; r < 4; ++r) {
      l_r[r] = l_r[r] * alpha[r] + rsum[r];
      o_acc[0][r] *= alpha[r];
      o_acc[1][r] *= alpha[r];
      o_acc[2][r] *= alpha[r];
      o_acc[3][r] *= alpha[r];
    }

    // ---- P -> wave-private LDS (C/D layout write), read back in A-frag layout
#pragma unroll
    for (int ns = 0; ns < 4; ++ns) {
#pragma unroll
      for (int r = 0; r < 4; ++r)
        Pl[wid][lg * 4 + r][ns * 16 + l15] = (bf16)sacc[ns][r];
    }
    asm volatile("s_waitcnt lgkmcnt(0)" ::: "memory");  // wave-local write->read fence

    // ---- O += P V : A = P[16x64], B = V[64xD]; Vt gives contiguous B-frag reads
#pragma unroll
    for (int h = 0; h < 2; ++h) {
      const bf16x8 pf = *(const bf16x8*)&Pl[wid][l15][h * 32 + lg * 8];
#pragma unroll
      for (int nd = 0; nd < 4; ++nd) {
        const bf16x8 vf = *(const bf16x8*)&Vt[nd * 16 + l15][h * 32 + lg * 8];
        o_acc[nd] = __builtin_amdgcn_mfma_f32_16x16x32_bf16(pf, vf, o_acc[nd], 0, 0, 0);
      }
    }
  }

  // ---- epilogue: O /= l, fp32 store
#pragma unroll
  for (int r = 0; r < 4; ++r) {
    const float inv = 1.0f / l_r[r];
    float* orow = Og + (size_t)(qbase + lg * 4 + r) * DHEAD;
#pragma unroll
    for (int nd = 0; nd < 4; ++nd)
      orow[nd * 16 + l15] = o_acc[nd][r] * inv;
  }
}

extern "C" void kernel_launch(void* const* d_in, const int* in_sizes, int n_in,
                              void* d_out, int out_size, void* d_ws, size_t ws_size,
                              hipStream_t stream) {
  const float* Q = (const float*)d_in[0];
  const float* K = (const float*)d_in[1];
  const float* V = (const float*)d_in[2];
  float* O = (float*)d_out;
  dim3 grid(1024), block(256);
  hipLaunchKernelGGL(attn_fwd, grid, block, 0, stream, Q, K, V, O);
}

// Round 4
// 215.280 us; speedup vs baseline: 1.1992x; 1.1992x over previous
//
#include <hip/hip_runtime.h>

typedef __bf16 bf16;
typedef __bf16 bf16x4 __attribute__((ext_vector_type(4)));
typedef __bf16 bf16x8 __attribute__((ext_vector_type(8)));
typedef float  f32x4  __attribute__((ext_vector_type(4)));

#define S_LEN 2048
#define DHEAD 64
#define BH    32
#define QB    128              // q rows per block: 4 waves x 32 rows
#define KB    64               // kv rows per tile
#define NT    (S_LEN / KB)     // 32 kv tiles
#define LDP   72               // P scratch leading dim (+8 pad)

static __device__ __forceinline__ void async_cp16(const bf16* g, bf16* l) {
  __builtin_amdgcn_global_load_lds(
      (const __attribute__((address_space(1))) void*)g,
      (__attribute__((address_space(3))) void*)l, 16, 0, 0);
}

static __device__ __forceinline__ f32x4 mfma_bf16(bf16x8 a, bf16x8 b, f32x4 c) {
  return __builtin_amdgcn_mfma_f32_16x16x32_bf16(a, b, c, 0, 0, 0);
}

// ---------- pre-pass 1: fp32 -> bf16 elementwise (for K) ----------
__global__ __launch_bounds__(256)
void cvt_bf16(const float* __restrict__ in, bf16* __restrict__ out, int n8) {
  const int i = blockIdx.x * 256 + threadIdx.x;
  if (i < n8) {
    const float4 a = ((const float4*)in)[2 * i];
    const float4 b = ((const float4*)in)[2 * i + 1];
    bf16x8 o;
    o[0] = (bf16)a.x; o[1] = (bf16)a.y; o[2] = (bf16)a.z; o[3] = (bf16)a.w;
    o[4] = (bf16)b.x; o[5] = (bf16)b.y; o[6] = (bf16)b.z; o[7] = (bf16)b.w;
    ((bf16x8*)out)[i] = o;
  }
}

// ---------- pre-pass 2: V [bh][S][D] fp32 -> Vt [bh][D][S] bf16 ----------
__global__ __launch_bounds__(256)
void vtrans(const float* __restrict__ V, bf16* __restrict__ Vt) {
  __shared__ bf16 t[64][72];
  const int bh = blockIdx.x >> 5;     // 0..31
  const int kt = blockIdx.x & 31;     // kv tile
  const float* src = V + ((size_t)bh * S_LEN + kt * 64) * DHEAD;
  bf16* dst = Vt + (size_t)bh * DHEAD * S_LEN + kt * 64;
  const int tid = threadIdx.x;
#pragma unroll
  for (int it = 0; it < 4; ++it) {
    const int i = tid + it * 256;         // 1024 float4 chunks
    const int r = i >> 4, c4 = (i & 15) << 2;
    const float4 v = *(const float4*)(src + (size_t)r * DHEAD + c4);
    bf16x4 o;
    o[0] = (bf16)v.x; o[1] = (bf16)v.y; o[2] = (bf16)v.z; o[3] = (bf16)v.w;
    *(bf16x4*)&t[r][c4] = o;
  }
  __syncthreads();
#pragma unroll
  for (int it = 0; it < 2; ++it) {
    const int j = tid + it * 256;         // 512 out-chunks of 8
    const int d = j >> 3, c8 = (j & 7) << 3;
    bf16x8 o;
#pragma unroll
    for (int e = 0; e < 8; ++e) o[e] = t[c8 + e][d];
    *(bf16x8*)(dst + (size_t)d * S_LEN + c8) = o;
  }
}

// ---------- main: flash attention, bf16 MFMA, async-staged swizzled LDS ----------
__global__ __launch_bounds__(256, 2)
void attn_fwd2(const float* __restrict__ Qg0, const bf16* __restrict__ Kb0,
               const bf16* __restrict__ Vt0, float* __restrict__ Og0) {
  __shared__ __align__(16) bf16 Kl[2][KB * DHEAD];   // [kv 64][d 64], xor-swizzled
  __shared__ __align__(16) bf16 Vl[2][DHEAD * KB];   // [d 64][kv 64], xor-swizzled
  __shared__ __align__(16) bf16 Pl[4][32][LDP];      // per-wave P scratch (+8 pad)

  const int tid = threadIdx.x, wid = tid >> 6, lane = tid & 63;
  const int l15 = lane & 15, lg = lane >> 4;
  const int bh = blockIdx.x >> 4;       // 0..31
  const int qb = blockIdx.x & 15;       // 0..15
  const int qbase = qb * QB + wid * 32;

  const float* Qg = Qg0 + (size_t)bh * S_LEN * DHEAD;
  const bf16* Kb = Kb0 + (size_t)bh * S_LEN * DHEAD;
  const bf16* Vt = Vt0 + (size_t)bh * DHEAD * S_LEN;
  float* Og = Og0 + (size_t)bh * S_LEN * DHEAD;

  // staging geometry: thread covers phys LDS chunks (row = srow + i*32, pc = lane&7)
  // linear LDS dest; source chunk is inverse-swizzled: cl = pc ^ (row&7)  [(i*32)&7==0]
  const int srow = wid * 8 + (lane >> 3);
  const int scl = ((lane & 7) ^ (srow & 7)) << 3;   // element offset in row
  const bf16* kg0 = Kb + (size_t)srow * DHEAD + scl;
  const bf16* vg0 = Vt + (size_t)srow * S_LEN + scl;

#define STAGE(b, t)                                                  \
  do {                                                               \
    const bf16* kg_ = kg0 + (size_t)(t) * KB * DHEAD;                \
    const bf16* vg_ = vg0 + (t) * KB;                                \
    async_cp16(kg_, &Kl[b][wid * 512]);                              \
    async_cp16(kg_ + 32 * DHEAD, &Kl[b][2048 + wid * 512]);          \
    async_cp16(vg_, &Vl[b][wid * 512]);                              \
    async_cp16(vg_ + (size_t)32 * S_LEN, &Vl[b][2048 + wid * 512]);  \
  } while (0)

  // ---- Q fragments (A-layout: row=l15, k=lg*8+j per 32-half), pre-scaled
  const float qscale = 0.125f * 1.44269504088896341f;
  bf16x8 qfrag[2][2];
#pragma unroll
  for (int rs = 0; rs < 2; ++rs) {
    const float* qrow = Qg + (size_t)(qbase + rs * 16 + l15) * DHEAD;
#pragma unroll
    for (int h = 0; h < 2; ++h) {
      const float* p = qrow + h * 32 + lg * 8;
      const float4 a = *(const float4*)(p);
      const float4 b = *(const float4*)(p + 4);
      bf16x8 f;
      f[0] = (bf16)(a.x * qscale); f[1] = (bf16)(a.y * qscale);
      f[2] = (bf16)(a.z * qscale); f[3] = (bf16)(a.w * qscale);
      f[4] = (bf16)(b.x * qscale); f[5] = (bf16)(b.y * qscale);
      f[6] = (bf16)(b.z * qscale); f[7] = (bf16)(b.w * qscale);
      qfrag[rs][h] = f;
    }
  }

  float m_r[2][4], l_r[2][4];
  f32x4 o_acc[2][4];
#pragma unroll
  for (int rs = 0; rs < 2; ++rs)
#pragma unroll
    for (int r = 0; r < 4; ++r) {
      m_r[rs][r] = -__builtin_inff();
      l_r[rs][r] = 0.f;
      o_acc[rs][r] = f32x4{0.f, 0.f, 0.f, 0.f};
    }

  const int kxor = (l15 & 7) << 4;   // byte-xor term: row&7 == l15&7 for all subtiles

  STAGE(0, 0);
  __syncthreads();

  for (int kt = 0; kt < NT; ++kt) {
    const int cur = kt & 1;
    if (kt + 1 < NT) STAGE(cur ^ 1, kt + 1);

    // ---- S = Q K^T (32x64 per wave)
    f32x4 sacc[2][4] = {};
#pragma unroll
    for (int ns = 0; ns < 4; ++ns) {
      const int krow = ns * 16 + l15;
#pragma unroll
      for (int h = 0; h < 2; ++h) {
        const int kb = krow * 128 + ((((h << 2) + lg) << 4) ^ kxor);
        const bf16x8 kf = *(const bf16x8*)((const char*)&Kl[cur][0] + kb);
        sacc[0][ns] = mfma_bf16(qfrag[0][h], kf, sacc[0][ns]);
        sacc[1][ns] = mfma_bf16(qfrag[1][h], kf, sacc[1][ns]);
      }
    }

    // ---- online softmax (C/D layout: col=l15, row=lg*4+r within 16-row subtile)
#pragma unroll
    for (int rs = 0; rs < 2; ++rs) {
      float rmax[4], alpha[4], rsum[4];
#pragma unroll
      for (int r = 0; r < 4; ++r)
        rmax[r] = fmaxf(fmaxf(sacc[rs][0][r], sacc[rs][1][r]),
                        fmaxf(sacc[rs][2][r], sacc[rs][3][r]));
#pragma unroll
      for (int off = 1; off < 16; off <<= 1)
#pragma unroll
        for (int r = 0; r < 4; ++r)
          rmax[r] = fmaxf(rmax[r], __shfl_xor(rmax[r], off));
#pragma unroll
      for (int r = 0; r < 4; ++r) {
        const float mn = fmaxf(m_r[rs][r], rmax[r]);
        alpha[r] = exp2f(m_r[rs][r] - mn);
        m_r[rs][r] = mn;
        rsum[r] = 0.f;
      }
#pragma unroll
      for (int ns = 0; ns < 4; ++ns)
#pragma unroll
        for (int r = 0; r < 4; ++r) {
          const float p = exp2f(sacc[rs][ns][r] - m_r[rs][r]);
          sacc[rs][ns][r] = p;
          rsum[r] += p;
        }
#pragma unroll
      for (int off = 1; off < 16; off <<= 1)
#pragma unroll
        for (int r = 0; r < 4; ++r)
          rsum[r] += __shfl_xor(rsum[r], off);
#pragma unroll
      for (int r = 0; r < 4; ++r) {
        l_r[rs][r] = l_r[rs][r] * alpha[r] + rsum[r];
        o_acc[rs][0][r] *= alpha[r];
        o_acc[rs][1][r] *= alpha[r];
        o_acc[rs][2][r] *= alpha[r];
        o_acc[rs][3][r] *= alpha[r];
      }
      // P -> wave-private LDS (C/D layout write)
#pragma unroll
      for (int ns = 0; ns < 4; ++ns)
#pragma unroll
        for (int r = 0; r < 4; ++r)
          Pl[wid][rs * 16 + lg * 4 + r][ns * 16 + l15] = (bf16)sacc[rs][ns][r];
    }
    asm volatile("s_waitcnt lgkmcnt(0)" ::: "memory");  // wave-local P write->read

    // ---- O += P V
#pragma unroll
    for (int h = 0; h < 2; ++h) {
      const bf16x8 pf0 = *(const bf16x8*)&Pl[wid][l15][h * 32 + lg * 8];
      const bf16x8 pf1 = *(const bf16x8*)&Pl[wid][16 + l15][h * 32 + lg * 8];
#pragma unroll
      for (int nd = 0; nd < 4; ++nd) {
        const int vrow = nd * 16 + l15;
        const int vb = vrow * 128 + ((((h << 2) + lg) << 4) ^ kxor);
        const bf16x8 vf = *(const bf16x8*)((const char*)&Vl[cur][0] + vb);
        o_acc[0][nd] = mfma_bf16(pf0, vf, o_acc[0][nd]);
        o_acc[1][nd] = mfma_bf16(pf1, vf, o_acc[1][nd]);
      }
    }
    __syncthreads();  // drains vmcnt(0): next tile staged; all reads of cur done
  }

  // ---- epilogue
#pragma unroll
  for (int rs = 0; rs < 2; ++rs)
#pragma unroll
    for (int r = 0; r < 4; ++r) {
      const float inv = 1.0f / l_r[rs][r];
      float* orow = Og + (size_t)(qbase + rs * 16 + lg * 4 + r) * DHEAD;
#pragma unroll
      for (int nd = 0; nd < 4; ++nd)
        orow[nd * 16 + l15] = o_acc[rs][nd][r] * inv;
    }
#undef STAGE
}

// ---------- fallback (round-1 kernel) if ws_size is too small ----------
__global__ __launch_bounds__(256, 2)
void attn_fb(const float* __restrict__ Qg0, const float* __restrict__ Kg0,
             const float* __restrict__ Vg0, float* __restrict__ Og0) {
  __shared__ __align__(16) bf16 Kl[KB][72];
  __shared__ __align__(16) bf16 Vt[DHEAD][72];
  __shared__ __align__(16) bf16 Pl[4][16][72];
  const int tid = threadIdx.x, wid = tid >> 6, lane = tid & 63;
  const int l15 = lane & 15, lg = lane >> 4;
  const int bh = blockIdx.x >> 5, qb = blockIdx.x & 31;
  const int qbase = qb * 64 + wid * 16;
  const size_t base = (size_t)bh * S_LEN * DHEAD;
  const float* Qg = Qg0 + base;
  const float* Kg = Kg0 + base;
  const float* Vg = Vg0 + base;
  float* Og = Og0 + base;
  const float qscale = 0.125f * 1.44269504088896341f;
  bf16x8 qfrag[2];
  {
    const float* qrow = Qg + (size_t)(qbase + l15) * DHEAD;
#pragma unroll
    for (int h = 0; h < 2; ++h) {
      const float* p = qrow + h * 32 + lg * 8;
      const float4 a = *(const float4*)(p);
      const float4 b = *(const float4*)(p + 4);
      bf16x8 f;
      f[0] = (bf16)(a.x * qscale); f[1] = (bf16)(a.y * qscale);
      f[2] = (bf16)(a.z * qscale); f[3] = (bf16)(a.w * qscale);
      f[4] = (bf16)(b.x * qscale); f[5] = (bf16)(b.y * qscale);
      f[6] = (bf16)(b.z * qscale); f[7] = (bf16)(b.w * qscale);
      qfrag[h] = f;
    }
  }
  float m_r[4], l_r[4];
  f32x4 o_acc[4];
#pragma unroll
  for (int r = 0; r < 4; ++r) {
    m_r[r] = -__builtin_inff();
    l_r[r] = 0.f;
    o_acc[r] = f32x4{0.f, 0.f, 0.f, 0.f};
  }
  for (int kt = 0; kt < NT; ++kt) {
    __syncthreads();
#pragma unroll
    for (int it = 0; it < 4; ++it) {
      const int i = tid + it * 256;
      const int row = i >> 4, c4 = (i & 15) << 2;
      const float4 kk = *(const float4*)(Kg + (size_t)(kt * KB + row) * DHEAD + c4);
      bf16x4 kb;
      kb[0] = (bf16)kk.x; kb[1] = (bf16)kk.y; kb[2] = (bf16)kk.z; kb[3] = (bf16)kk.w;
      *(bf16x4*)&Kl[row][c4] = kb;
      const float4 vv = *(const float4*)(Vg + (size_t)(kt * KB + row) * DHEAD + c4);
      Vt[c4 + 0][row] = (bf16)vv.x;
      Vt[c4 + 1][row] = (bf16)vv.y;
      Vt[c4 + 2][row] = (bf16)vv.z;
      Vt[c4 + 3][row] = (bf16)vv.w;
    }
    __syncthreads();
    f32x4 sacc[4] = {};
#pragma unroll
    for (int ns = 0; ns < 4; ++ns)
#pragma unroll
      for (int h = 0; h < 2; ++h) {
        const bf16x8 kf = *(const bf16x8*)&Kl[ns * 16 + l15][h * 32 + lg * 8];
        sacc[ns] = mfma_bf16(qfrag[h], kf, sacc[ns]);
      }
    float rmax[4], alpha[4], rsum[4];
#pragma unroll
    for (int r = 0; r < 4; ++r)
      rmax[r] = fmaxf(fmaxf(sacc[0][r], sacc[1][r]), fmaxf(sacc[2][r], sacc[3][r]));
#pragma unroll
    for (int off = 1; off < 16; off <<= 1)
#pragma unroll
      for (int r = 0; r < 4; ++r)
        rmax[r] = fmaxf(rmax[r], __shfl_xor(rmax[r], off));
#pragma unroll
    for (int r = 0; r < 4; ++r) {
      const float mn = fmaxf(m_r[r], rmax[r]);
      alpha[r] = exp2f(m_r[r] - mn);
      m_r[r] = mn;
      rsum[r] = 0.f;
    }
#pragma unroll
    for (int ns = 0; ns < 4; ++ns)
#pragma unroll
      for (int r = 0; r < 4; ++r) {
        const float p = exp2f(sacc[ns][r] - m_r[r]);
        sacc[ns][r] = p;
        rsum[r] += p;
      }
#pragma unroll
    for (int off = 1; off < 16; off <<= 1)
#pragma unroll
      for (int r = 0; r < 4; ++r)
        rsum[r] += __shfl_xor(rsum[r], off);
#pragma unroll
    for (int r = 0; r < 4; ++r) {
      l_r[r] = l_r[r] * alpha[r] + rsum[r];
      o_acc[0][r] *= alpha[r];
      o_acc[1][r] *= alpha[r];
      o_acc[2][r] *= alpha[r];
      o_acc[3][r] *= alpha[r];
    }
#pragma unroll
    for (int ns = 0; ns < 4; ++ns)
#pragma unroll
      for (int r = 0; r < 4; ++r)
        Pl[wid][lg * 4 + r][ns * 16 + l15] = (bf16)sacc[ns][r];
    asm volatile("s_waitcnt lgkmcnt(0)" ::: "memory");
#pragma unroll
    for (int h = 0; h < 2; ++h) {
      const bf16x8 pf = *(const bf16x8*)&Pl[wid][l15][h * 32 + lg * 8];
#pragma unroll
      for (int nd = 0; nd < 4; ++nd) {
        const bf16x8 vf = *(const bf16x8*)&Vt[nd * 16 + l15][h * 32 + lg * 8];
        o_acc[nd] = mfma_bf16(pf, vf, o_acc[nd]);
      }
    }
  }
#pragma unroll
  for (int r = 0; r < 4; ++r) {
    const float inv = 1.0f / l_r[r];
    float* orow = Og + (size_t)(qbase + lg * 4 + r) * DHEAD;
#pragma unroll
    for (int nd = 0; nd < 4; ++nd)
      orow[nd * 16 + l15] = o_acc[nd][r] * inv;
  }
}

extern "C" void kernel_launch(void* const* d_in, const int* in_sizes, int n_in,
                              void* d_out, int out_size, void* d_ws, size_t ws_size,
                              hipStream_t stream) {
  const float* Q = (const float*)d_in[0];
  const float* K = (const float*)d_in[1];
  const float* V = (const float*)d_in[2];
  float* O = (float*)d_out;

  const size_t elems = (size_t)BH * S_LEN * DHEAD;   // 4,194,304
  const size_t bf16_bytes = elems * 2;               // 8,388,608
  if (ws_size >= 2 * bf16_bytes) {
    bf16* Kb = (bf16*)d_ws;
    bf16* Vt = (bf16*)((char*)d_ws + bf16_bytes);
    hipLaunchKernelGGL(cvt_bf16, dim3((int)(elems / 8 / 256)), dim3(256), 0, stream,
                       K, Kb, (int)(elems / 8));
    hipLaunchKernelGGL(vtrans, dim3(BH * 32), dim3(256), 0, stream, V, Vt);
    hipLaunchKernelGGL(attn_fwd2, dim3(BH * (S_LEN / QB)), dim3(256), 0, stream,
                       Q, Kb, Vt, O);
  } else {
    hipLaunchKernelGGL(attn_fb, dim3(1024), dim3(256), 0, stream, Q, K, V, O);
  }
}

// Round 8
// 177.842 us; speedup vs baseline: 1.4517x; 1.2105x over previous
//
#include <hip/hip_runtime.h>

typedef __bf16 bf16;
typedef __bf16 bf16x4 __attribute__((ext_vector_type(4)));
typedef __bf16 bf16x8 __attribute__((ext_vector_type(8)));
typedef float  f32x4  __attribute__((ext_vector_type(4)));

#define S_LEN 2048
#define DHEAD 64
#define BH    32
#define QB    64               // q rows per block: 4 waves x 16 rows
#define KB    64               // kv rows per tile
#define NT    (S_LEN / KB)     // 32 kv tiles
#define LDP   72               // P scratch leading dim (+8 pad)

static __device__ __forceinline__ void async_cp16(const bf16* g, bf16* l) {
  __builtin_amdgcn_global_load_lds(
      (const __attribute__((address_space(1))) void*)g,
      (__attribute__((address_space(3))) void*)l, 16, 0, 0);
}

static __device__ __forceinline__ f32x4 mfma_bf16(bf16x8 a, bf16x8 b, f32x4 c) {
  return __builtin_amdgcn_mfma_f32_16x16x32_bf16(a, b, c, 0, 0, 0);
}

// ---------- pre-pass 1: fp32 -> bf16 elementwise (for K) ----------
__global__ __launch_bounds__(256)
void cvt_bf16(const float* __restrict__ in, bf16* __restrict__ out, int n8) {
  const int i = blockIdx.x * 256 + threadIdx.x;
  if (i < n8) {
    const float4 a = ((const float4*)in)[2 * i];
    const float4 b = ((const float4*)in)[2 * i + 1];
    bf16x8 o;
    o[0] = (bf16)a.x; o[1] = (bf16)a.y; o[2] = (bf16)a.z; o[3] = (bf16)a.w;
    o[4] = (bf16)b.x; o[5] = (bf16)b.y; o[6] = (bf16)b.z; o[7] = (bf16)b.w;
    ((bf16x8*)out)[i] = o;
  }
}

// ---------- pre-pass 2: V [bh][S][D] fp32 -> Vt [bh][D][S] bf16 ----------
__global__ __launch_bounds__(256)
void vtrans(const float* __restrict__ V, bf16* __restrict__ Vt) {
  __shared__ bf16 t[64][72];
  const int bh = blockIdx.x >> 5;     // 0..31
  const int kt = blockIdx.x & 31;     // kv tile
  const float* src = V + ((size_t)bh * S_LEN + kt * 64) * DHEAD;
  bf16* dst = Vt + (size_t)bh * DHEAD * S_LEN + kt * 64;
  const int tid = threadIdx.x;
#pragma unroll
  for (int it = 0; it < 4; ++it) {
    const int i = tid + it * 256;         // 1024 float4 chunks
    const int r = i >> 4, c4 = (i & 15) << 2;
    const float4 v = *(const float4*)(src + (size_t)r * DHEAD + c4);
    bf16x4 o;
    o[0] = (bf16)v.x; o[1] = (bf16)v.y; o[2] = (bf16)v.z; o[3] = (bf16)v.w;
    *(bf16x4*)&t[r][c4] = o;
  }
  __syncthreads();
#pragma unroll
  for (int it = 0; it < 2; ++it) {
    const int j = tid + it * 256;         // 512 out-chunks of 8
    const int d = j >> 3, c8 = (j & 7) << 3;
    bf16x8 o;
#pragma unroll
    for (int e = 0; e < 8; ++e) o[e] = t[c8 + e][d];
    *(bf16x8*)(dst + (size_t)d * S_LEN + c8) = o;
  }
}

// ---------- main: flash attention, swapped QK^T, in-lane softmax, defer-max ----
__global__ __launch_bounds__(256, 3)
void attn_fwd3(const float* __restrict__ Qg0, const bf16* __restrict__ Kb0,
               const bf16* __restrict__ Vt0, float* __restrict__ Og0) {
  __shared__ __align__(16) bf16 Kl[2][KB * DHEAD];   // [kv 64][d 64], xor-swizzled
  __shared__ __align__(16) bf16 Vl[2][DHEAD * KB];   // [d 64][kv 64], xor-swizzled
  __shared__ __align__(16) bf16 Pl[4][16][LDP];      // per-wave P [q 16][kv 64+pad]

  const int tid = threadIdx.x, wid = tid >> 6, lane = tid & 63;
  const int l15 = lane & 15, lg = lane >> 4;
  const int bh = blockIdx.x >> 5;       // 0..31
  const int qb = blockIdx.x & 31;       // 0..31
  const int qbase = qb * QB + wid * 16;

  const float* Qg = Qg0 + (size_t)bh * S_LEN * DHEAD;
  const bf16* Kb = Kb0 + (size_t)bh * S_LEN * DHEAD;
  const bf16* Vt = Vt0 + (size_t)bh * DHEAD * S_LEN;
  float* Og = Og0 + (size_t)bh * S_LEN * DHEAD;

  // staging: linear LDS dest; global source chunk inverse-swizzled (rule #21)
  const int srow = wid * 8 + (lane >> 3);           // 0..31
  const int scl = ((lane & 7) ^ (srow & 7)) << 3;   // element offset in row
  const bf16* kg0 = Kb + (size_t)srow * DHEAD + scl;
  const bf16* vg0 = Vt + (size_t)srow * S_LEN + scl;

#define STAGE(b, t)                                                  \
  do {                                                               \
    const bf16* kg_ = kg0 + (size_t)(t) * KB * DHEAD;                \
    const bf16* vg_ = vg0 + (t) * KB;                                \
    async_cp16(kg_, &Kl[b][wid * 512]);                              \
    async_cp16(kg_ + 32 * DHEAD, &Kl[b][2048 + wid * 512]);          \
    async_cp16(vg_, &Vl[b][wid * 512]);                              \
    async_cp16(vg_ + (size_t)32 * S_LEN, &Vl[b][2048 + wid * 512]);  \
  } while (0)

  // ---- Q fragments: lane l15 -> q-row (B-operand col), k = h*32 + lg*8 + j
  const float qscale = 0.125f * 1.44269504088896341f;
  bf16x8 qfrag[2];
  {
    const float* qrow = Qg + (size_t)(qbase + l15) * DHEAD;
#pragma unroll
    for (int h = 0; h < 2; ++h) {
      const float* p = qrow + h * 32 + lg * 8;
      const float4 a = *(const float4*)(p);
      const float4 b = *(const float4*)(p + 4);
      bf16x8 f;
      f[0] = (bf16)(a.x * qscale); f[1] = (bf16)(a.y * qscale);
      f[2] = (bf16)(a.z * qscale); f[3] = (bf16)(a.w * qscale);
      f[4] = (bf16)(b.x * qscale); f[5] = (bf16)(b.y * qscale);
      f[6] = (bf16)(b.z * qscale); f[7] = (bf16)(b.w * qscale);
      qfrag[h] = f;
    }
  }

  // softmax state in LANE space: this lane tracks q-row (qbase + l15)
  float m_l = -__builtin_inff();
  float l_l = 0.f;
  // o_acc in REG space: row q = lg*4 + r, col d = nd*16 + l15
  f32x4 o_acc[4];
#pragma unroll
  for (int nd = 0; nd < 4; ++nd) o_acc[nd] = f32x4{0.f, 0.f, 0.f, 0.f};

  const int kxor = (l15 & 7) << 4;   // byte-xor: row&7 == l15&7 for all subtiles

  STAGE(0, 0);
  __syncthreads();

  for (int kt = 0; kt < NT; ++kt) {
    const int cur = kt & 1;
    if (kt + 1 < NT) STAGE(cur ^ 1, kt + 1);

    // ---- S^T = K Q^T : D[kv][q]; lane holds kv = ns*16 + lg*4 + r, q = l15
    f32x4 sacc[4] = {};
    __builtin_amdgcn_s_setprio(1);
#pragma unroll
    for (int ns = 0; ns < 4; ++ns) {
      const int krow = ns * 16 + l15;
#pragma unroll
      for (int h = 0; h < 2; ++h) {
        const int kb = krow * 128 + ((((h << 2) + lg) << 4) ^ kxor);
        const bf16x8 kf = *(const bf16x8*)((const char*)&Kl[cur][0] + kb);
        sacc[ns] = mfma_bf16(kf, qfrag[h], sacc[ns]);   // swapped operands
      }
    }
    __builtin_amdgcn_s_setprio(0);

    // ---- softmax: row (q=l15) spread over {regs r, subtiles ns} x 4 lanes (lg)
    float pmax = sacc[0][0];
#pragma unroll
    for (int ns = 0; ns < 4; ++ns)
#pragma unroll
      for (int r = 0; r < 4; ++r) pmax = fmaxf(pmax, sacc[ns][r]);
    pmax = fmaxf(pmax, __shfl_xor(pmax, 16));
    pmax = fmaxf(pmax, __shfl_xor(pmax, 32));

    // defer-max: rescale only when some row's max grew by > 8 (in log2 units)
    if (!__all(pmax <= m_l + 8.f)) {
      const float mn = fmaxf(m_l, pmax);
      const float alpha = exp2f(m_l - mn);   // first tile: exp2(-inf) = 0
      m_l = mn;
      l_l *= alpha;
#pragma unroll
      for (int r = 0; r < 4; ++r) {
        // alpha for o-row q = lg*4 + r lives at lane with l15 = lg*4 + r
        const float a_r = __shfl(alpha, (lane & 48) | (((lane >> 4) & 3) * 4 + r));
        o_acc[0][r] *= a_r;
        o_acc[1][r] *= a_r;
        o_acc[2][r] *= a_r;
        o_acc[3][r] *= a_r;
      }
    }

    float rsum = 0.f;
#pragma unroll
    for (int ns = 0; ns < 4; ++ns) {
#pragma unroll
      for (int r = 0; r < 4; ++r) {
        const float p = exp2f(sacc[ns][r] - m_l);
        sacc[ns][r] = p;
        rsum += p;
      }
      // P write: row q = l15, kv = ns*16 + lg*4 + r -> 4 contiguous bf16 (8B)
      bf16x4 pw;
      pw[0] = (bf16)sacc[ns][0]; pw[1] = (bf16)sacc[ns][1];
      pw[2] = (bf16)sacc[ns][2]; pw[3] = (bf16)sacc[ns][3];
      *(bf16x4*)&Pl[wid][l15][ns * 16 + lg * 4] = pw;
    }
    rsum += __shfl_xor(rsum, 16);
    rsum += __shfl_xor(rsum, 32);
    l_l += rsum;

    asm volatile("s_waitcnt lgkmcnt(0)" ::: "memory");  // wave-local P write->read

    // ---- O += P V : A = P[16q x 64kv], B = V[64kv x 64d]
    __builtin_amdgcn_s_setprio(1);
#pragma unroll
    for (int h = 0; h < 2; ++h) {
      const bf16x8 pf = *(const bf16x8*)&Pl[wid][l15][h * 32 + lg * 8];
#pragma unroll
      for (int nd = 0; nd < 4; ++nd) {
        const int vrow = nd * 16 + l15;
        const int vb = vrow * 128 + ((((h << 2) + lg) << 4) ^ kxor);
        const bf16x8 vf = *(const bf16x8*)((const char*)&Vl[cur][0] + vb);
        o_acc[nd] = mfma_bf16(pf, vf, o_acc[nd]);
      }
    }
    __builtin_amdgcn_s_setprio(0);
    __syncthreads();  // drains vmcnt(0): next tile staged; all reads of cur done
  }

  // ---- epilogue: l for o-row q = lg*4 + r lives at lane l15 = lg*4 + r
#pragma unroll
  for (int r = 0; r < 4; ++r) {
    const float l_r = __shfl(l_l, (lane & 48) | (((lane >> 4) & 3) * 4 + r));
    const float inv = 1.0f / l_r;
    float* orow = Og + (size_t)(qbase + lg * 4 + r) * DHEAD;
#pragma unroll
    for (int nd = 0; nd < 4; ++nd)
      orow[nd * 16 + l15] = o_acc[nd][r] * inv;
  }
#undef STAGE
}

// ---------- fallback (round-1 kernel) if ws_size is too small ----------
__global__ __launch_bounds__(256, 2)
void attn_fb(const float* __restrict__ Qg0, const float* __restrict__ Kg0,
             const float* __restrict__ Vg0, float* __restrict__ Og0) {
  __shared__ __align__(16) bf16 Kl[KB][72];
  __shared__ __align__(16) bf16 Vt[DHEAD][72];
  __shared__ __align__(16) bf16 Pl[4][16][72];
  const int tid = threadIdx.x, wid = tid >> 6, lane = tid & 63;
  const int l15 = lane & 15, lg = lane >> 4;
  const int bh = blockIdx.x >> 5, qb = blockIdx.x & 31;
  const int qbase = qb * 64 + wid * 16;
  const size_t base = (size_t)bh * S_LEN * DHEAD;
  const float* Qg = Qg0 + base;
  const float* Kg = Kg0 + base;
  const float* Vg = Vg0 + base;
  float* Og = Og0 + base;
  const float qscale = 0.125f * 1.44269504088896341f;
  bf16x8 qfrag[2];
  {
    const float* qrow = Qg + (size_t)(qbase + l15) * DHEAD;
#pragma unroll
    for (int h = 0; h < 2; ++h) {
      const float* p = qrow + h * 32 + lg * 8;
      const float4 a = *(const float4*)(p);
      const float4 b = *(const float4*)(p + 4);
      bf16x8 f;
      f[0] = (bf16)(a.x * qscale); f[1] = (bf16)(a.y * qscale);
      f[2] = (bf16)(a.z * qscale); f[3] = (bf16)(a.w * qscale);
      f[4] = (bf16)(b.x * qscale); f[5] = (bf16)(b.y * qscale);
      f[6] = (bf16)(b.z * qscale); f[7] = (bf16)(b.w * qscale);
      qfrag[h] = f;
    }
  }
  float m_r[4], l_r[4];
  f32x4 o_acc[4];
#pragma unroll
  for (int r = 0; r < 4; ++r) {
    m_r[r] = -__builtin_inff();
    l_r[r] = 0.f;
    o_acc[r] = f32x4{0.f, 0.f, 0.f, 0.f};
  }
  for (int kt = 0; kt < NT; ++kt) {
    __syncthreads();
#pragma unroll
    for (int it = 0; it < 4; ++it) {
      const int i = tid + it * 256;
      const int row = i >> 4, c4 = (i & 15) << 2;
      const float4 kk = *(const float4*)(Kg + (size_t)(kt * KB + row) * DHEAD + c4);
      bf16x4 kb;
      kb[0] = (bf16)kk.x; kb[1] = (bf16)kk.y; kb[2] = (bf16)kk.z; kb[3] = (bf16)kk.w;
      *(bf16x4*)&Kl[row][c4] = kb;
      const float4 vv = *(const float4*)(Vg + (size_t)(kt * KB + row) * DHEAD + c4);
      Vt[c4 + 0][row] = (bf16)vv.x;
      Vt[c4 + 1][row] = (bf16)vv.y;
      Vt[c4 + 2][row] = (bf16)vv.z;
      Vt[c4 + 3][row] = (bf16)vv.w;
    }
    __syncthreads();
    f32x4 sacc[4] = {};
#pragma unroll
    for (int ns = 0; ns < 4; ++ns)
#pragma unroll
      for (int h = 0; h < 2; ++h) {
        const bf16x8 kf = *(const bf16x8*)&Kl[ns * 16 + l15][h * 32 + lg * 8];
        sacc[ns] = mfma_bf16(qfrag[h], kf, sacc[ns]);
      }
    float rmax[4], alpha[4], rsum[4];
#pragma unroll
    for (int r = 0; r < 4; ++r)
      rmax[r] = fmaxf(fmaxf(sacc[0][r], sacc[1][r]), fmaxf(sacc[2][r], sacc[3][r]));
#pragma unroll
    for (int off = 1; off < 16; off <<= 1)
#pragma unroll
      for (int r = 0; r < 4; ++r)
        rmax[r] = fmaxf(rmax[r], __shfl_xor(rmax[r], off));
#pragma unroll
    for (int r = 0; r < 4; ++r) {
      const float mn = fmaxf(m_r[r], rmax[r]);
      alpha[r] = exp2f(m_r[r] - mn);
      m_r[r] = mn;
      rsum[r] = 0.f;
    }
#pragma unroll
    for (int ns = 0; ns < 4; ++ns)
#pragma unroll
      for (int r = 0; r < 4; ++r) {
        const float p = exp2f(sacc[ns][r] - m_r[r]);
        sacc[ns][r] = p;
        rsum[r] += p;
      }
#pragma unroll
    for (int off = 1; off < 16; off <<= 1)
#pragma unroll
      for (int r = 0; r < 4; ++r)
        rsum[r] += __shfl_xor(rsum[r], off);
#pragma unroll
    for (int r = 0; r < 4; ++r) {
      l_r[r] = l_r[r] * alpha[r] + rsum[r];
      o_acc[0][r] *= alpha[r];
      o_acc[1][r] *= alpha[r];
      o_acc[2][r] *= alpha[r];
      o_acc[3][r] *= alpha[r];
    }
#pragma unroll
    for (int ns = 0; ns < 4; ++ns)
#pragma unroll
      for (int r = 0; r < 4; ++r)
        Pl[wid][lg * 4 + r][ns * 16 + l15] = (bf16)sacc[ns][r];
    asm volatile("s_waitcnt lgkmcnt(0)" ::: "memory");
#pragma unroll
    for (int h = 0; h < 2; ++h) {
      const bf16x8 pf = *(const bf16x8*)&Pl[wid][l15][h * 32 + lg * 8];
#pragma unroll
      for (int nd = 0; nd < 4; ++nd) {
        const bf16x8 vf = *(const bf16x8*)&Vt[nd * 16 + l15][h * 32 + lg * 8];
        o_acc[nd] = mfma_bf16(pf, vf, o_acc[nd]);
      }
    }
  }
#pragma unroll
  for (int r = 0; r < 4; ++r) {
    const float inv = 1.0f / l_r[r];
    float* orow = Og + (size_t)(qbase + lg * 4 + r) * DHEAD;
#pragma unroll
    for (int nd = 0; nd < 4; ++nd)
      orow[nd * 16 + l15] = o_acc[nd][r] * inv;
  }
}

extern "C" void kernel_launch(void* const* d_in, const int* in_sizes, int n_in,
                              void* d_out, int out_size, void* d_ws, size_t ws_size,
                              hipStream_t stream) {
  const float* Q = (const float*)d_in[0];
  const float* K = (const float*)d_in[1];
  const float* V = (const float*)d_in[2];
  float* O = (float*)d_out;

  const size_t elems = (size_t)BH * S_LEN * DHEAD;   // 4,194,304
  const size_t bf16_bytes = elems * 2;               // 8,388,608
  if (ws_size >= 2 * bf16_bytes) {
    bf16* Kb = (bf16*)d_ws;
    bf16* Vt = (bf16*)((char*)d_ws + bf16_bytes);
    hipLaunchKernelGGL(cvt_bf16, dim3((int)(elems / 8 / 256)), dim3(256), 0, stream,
                       K, Kb, (int)(elems / 8));
    hipLaunchKernelGGL(vtrans, dim3(BH * 32), dim3(256), 0, stream, V, Vt);
    hipLaunchKernelGGL(attn_fwd3, dim3(BH * (S_LEN / QB)), dim3(256), 0, stream,
                       Q, Kb, Vt, O);
  } else {
    hipLaunchKernelGGL(attn_fb, dim3(1024), dim3(256), 0, stream, Q, K, V, O);
  }
}

// Round 9
// 142.869 us; speedup vs baseline: 1.8070x; 1.2448x over previous
//
#include <hip/hip_runtime.h>

typedef __bf16 bf16;
typedef __bf16 bf16x4 __attribute__((ext_vector_type(4)));
typedef __bf16 bf16x8 __attribute__((ext_vector_type(8)));
typedef float  f32x4  __attribute__((ext_vector_type(4)));

#define S_LEN 2048
#define DHEAD 64
#define BH    32
#define QB    128              // q rows per block: 8 waves x 16 rows
#define KB    64               // kv rows per tile
#define NT    (S_LEN / KB)     // 32 kv tiles

static __device__ __forceinline__ void async_cp16(const bf16* g, bf16* l) {
  __builtin_amdgcn_global_load_lds(
      (const __attribute__((address_space(1))) void*)g,
      (__attribute__((address_space(3))) void*)l, 16, 0, 0);
}

static __device__ __forceinline__ f32x4 mfma_bf16(bf16x8 a, bf16x8 b, f32x4 c) {
  return __builtin_amdgcn_mfma_f32_16x16x32_bf16(a, b, c, 0, 0, 0);
}

// ---------- pre-pass: K fp32->bf16 copy + V fp32->bf16 transpose, per tile ----
__global__ __launch_bounds__(256)
void kv_prep(const float* __restrict__ K, const float* __restrict__ V,
             bf16* __restrict__ Kb, bf16* __restrict__ Vt) {
  __shared__ bf16 t[64][72];
  const int bh = blockIdx.x >> 5;     // 0..31
  const int kt = blockIdx.x & 31;     // kv tile
  const int tid = threadIdx.x;
  const size_t tbase = ((size_t)bh * S_LEN + kt * 64) * DHEAD;

  // K: straight convert, 64x64 tile = 512 chunks of 8 floats
  const float* ksrc = K + tbase;
  bf16* kdst = Kb + tbase;
#pragma unroll
  for (int it = 0; it < 2; ++it) {
    const int i = tid + it * 256;       // 0..511
    const float4 a = ((const float4*)ksrc)[2 * i];
    const float4 b = ((const float4*)ksrc)[2 * i + 1];
    bf16x8 o;
    o[0] = (bf16)a.x; o[1] = (bf16)a.y; o[2] = (bf16)a.z; o[3] = (bf16)a.w;
    o[4] = (bf16)b.x; o[5] = (bf16)b.y; o[6] = (bf16)b.z; o[7] = (bf16)b.w;
    ((bf16x8*)kdst)[i] = o;
  }

  // V: transpose to [bh][d][S]
  const float* vsrc = V + tbase;
  bf16* vdst = Vt + (size_t)bh * DHEAD * S_LEN + kt * 64;
#pragma unroll
  for (int it = 0; it < 4; ++it) {
    const int i = tid + it * 256;       // 1024 float4 chunks
    const int r = i >> 4, c4 = (i & 15) << 2;
    const float4 v = *(const float4*)(vsrc + (size_t)r * DHEAD + c4);
    bf16x4 o;
    o[0] = (bf16)v.x; o[1] = (bf16)v.y; o[2] = (bf16)v.z; o[3] = (bf16)v.w;
    *(bf16x4*)&t[r][c4] = o;
  }
  __syncthreads();
#pragma unroll
  for (int it = 0; it < 2; ++it) {
    const int j = tid + it * 256;       // 512 out-chunks of 8
    const int d = j >> 3, c8 = (j & 7) << 3;
    bf16x8 o;
#pragma unroll
    for (int e = 0; e < 8; ++e) o[e] = t[c8 + e][d];
    *(bf16x8*)(vdst + (size_t)d * S_LEN + c8) = o;
  }
}

// ---------- main: flash attention, swapped QK^T, in-lane softmax, defer-max ----
// 8 waves/block, 16 q-rows per wave; K/V xor-swizzled LDS; P xor-swizzled LDS.
__global__ __launch_bounds__(512, 4)
void attn_fwd4(const float* __restrict__ Qg0, const bf16* __restrict__ Kb0,
               const bf16* __restrict__ Vt0, float* __restrict__ Og0) {
  __shared__ __align__(16) bf16 Kl[2][KB * DHEAD];   // [kv 64][d 64], xor-swizzled
  __shared__ __align__(16) bf16 Vl[2][DHEAD * KB];   // [d 64][kv 64], xor-swizzled
  __shared__ __align__(16) bf16 Pl[8][16][64];       // per-wave P, xor-swizzled

  const int tid = threadIdx.x, wid = tid >> 6, lane = tid & 63;
  const int l15 = lane & 15, lg = lane >> 4;
  const int bh = blockIdx.x >> 4;       // 0..31
  const int qb = blockIdx.x & 15;       // 0..15
  const int qbase = qb * QB + wid * 16;

  const float* Qg = Qg0 + (size_t)bh * S_LEN * DHEAD;
  const bf16* Kb = Kb0 + (size_t)bh * S_LEN * DHEAD;
  const bf16* Vt = Vt0 + (size_t)bh * DHEAD * S_LEN;
  float* Og = Og0 + (size_t)bh * S_LEN * DHEAD;

  // staging: linear LDS dest; global source chunk inverse-swizzled (rule #21)
  const int srow = wid * 8 + (lane >> 3);           // 0..63
  const int scl = ((lane & 7) ^ (srow & 7)) << 3;   // element offset in row
  const bf16* kg0 = Kb + (size_t)srow * DHEAD + scl;
  const bf16* vg0 = Vt + (size_t)srow * S_LEN + scl;

#define STAGE(b, t)                                  \
  do {                                               \
    async_cp16(kg0 + (size_t)(t) * KB * DHEAD, &Kl[b][wid * 512]); \
    async_cp16(vg0 + (t) * KB, &Vl[b][wid * 512]);   \
  } while (0)

  // ---- Q fragments: lane l15 -> q-row (B-operand col), k = h*32 + lg*8 + j
  const float qscale = 0.125f * 1.44269504088896341f;
  bf16x8 qfrag[2];
  {
    const float* qrow = Qg + (size_t)(qbase + l15) * DHEAD;
#pragma unroll
    for (int h = 0; h < 2; ++h) {
      const float* p = qrow + h * 32 + lg * 8;
      const float4 a = *(const float4*)(p);
      const float4 b = *(const float4*)(p + 4);
      bf16x8 f;
      f[0] = (bf16)(a.x * qscale); f[1] = (bf16)(a.y * qscale);
      f[2] = (bf16)(a.z * qscale); f[3] = (bf16)(a.w * qscale);
      f[4] = (bf16)(b.x * qscale); f[5] = (bf16)(b.y * qscale);
      f[6] = (bf16)(b.z * qscale); f[7] = (bf16)(b.w * qscale);
      qfrag[h] = f;
    }
  }

  // softmax state in LANE space: this lane tracks q-row (qbase + l15)
  float m_l = -__builtin_inff();
  float l_l = 0.f;
  // o_acc in REG space: row q = lg*4 + r, col d = nd*16 + l15
  f32x4 o_acc[4];
#pragma unroll
  for (int nd = 0; nd < 4; ++nd) o_acc[nd] = f32x4{0.f, 0.f, 0.f, 0.f};

  const int kxor = (l15 & 7) << 4;      // K/V read swizzle: row&7 == l15&7
  const int pswz = (l15 & 7) << 4;      // P swizzle within q-row l15
  char* pbase = (char*)&Pl[wid][0][0] + l15 * 128;

  STAGE(0, 0);
  __syncthreads();

  for (int kt = 0; kt < NT; ++kt) {
    const int cur = kt & 1;
    if (kt + 1 < NT) STAGE(cur ^ 1, kt + 1);

    // ---- S^T = K Q^T : D[kv][q]; lane holds kv = ns*16 + lg*4 + r, q = l15
    f32x4 sacc[4] = {};
    __builtin_amdgcn_s_setprio(1);
#pragma unroll
    for (int ns = 0; ns < 4; ++ns) {
      const int krow = ns * 16 + l15;
#pragma unroll
      for (int h = 0; h < 2; ++h) {
        const int kb = krow * 128 + ((((h << 2) + lg) << 4) ^ kxor);
        const bf16x8 kf = *(const bf16x8*)((const char*)&Kl[cur][0] + kb);
        sacc[ns] = mfma_bf16(kf, qfrag[h], sacc[ns]);   // swapped operands
      }
    }
    __builtin_amdgcn_s_setprio(0);

    // ---- softmax: row (q=l15) spread over {regs r, subtiles ns} x 4 lanes (lg)
    float pmax = sacc[0][0];
#pragma unroll
    for (int ns = 0; ns < 4; ++ns)
#pragma unroll
      for (int r = 0; r < 4; ++r) pmax = fmaxf(pmax, sacc[ns][r]);
    pmax = fmaxf(pmax, __shfl_xor(pmax, 16));
    pmax = fmaxf(pmax, __shfl_xor(pmax, 32));

    // defer-max: rescale only when some row's max grew by > 8 (in log2 units)
    if (!__all(pmax <= m_l + 8.f)) {
      const float mn = fmaxf(m_l, pmax);
      const float alpha = __builtin_amdgcn_exp2f(m_l - mn);  // first tile: 0
      m_l = mn;
      l_l *= alpha;
#pragma unroll
      for (int r = 0; r < 4; ++r) {
        // alpha for o-row q = lg*4 + r lives at lane with l15 = lg*4 + r
        const float a_r = __shfl(alpha, (lane & 48) | (((lane >> 4) & 3) * 4 + r));
        o_acc[0][r] *= a_r;
        o_acc[1][r] *= a_r;
        o_acc[2][r] *= a_r;
        o_acc[3][r] *= a_r;
      }
    }

    float rsum = 0.f;
#pragma unroll
    for (int ns = 0; ns < 4; ++ns) {
#pragma unroll
      for (int r = 0; r < 4; ++r) {
        const float p = __builtin_amdgcn_exp2f(sacc[ns][r] - m_l);
        sacc[ns][r] = p;
        rsum += p;
      }
      // P write: row q = l15, kv = ns*16 + lg*4 + r -> 8B chunk, xor-swizzled
      bf16x4 pw;
      pw[0] = (bf16)sacc[ns][0]; pw[1] = (bf16)sacc[ns][1];
      pw[2] = (bf16)sacc[ns][2]; pw[3] = (bf16)sacc[ns][3];
      *(bf16x4*)(pbase + (((ns << 5) + (lg << 3)) ^ pswz)) = pw;
    }
    rsum += __shfl_xor(rsum, 16);
    rsum += __shfl_xor(rsum, 32);
    l_l += rsum;

    asm volatile("s_waitcnt lgkmcnt(0)" ::: "memory");  // wave-local P write->read

    // ---- O += P V : A = P[16q x 64kv], B = V[64kv x 64d]
    __builtin_amdgcn_s_setprio(1);
#pragma unroll
    for (int h = 0; h < 2; ++h) {
      const bf16x8 pf = *(const bf16x8*)(pbase + (((h << 6) + (lg << 4)) ^ pswz));
#pragma unroll
      for (int nd = 0; nd < 4; ++nd) {
        const int vrow = nd * 16 + l15;
        const int vb = vrow * 128 + ((((h << 2) + lg) << 4) ^ kxor);
        const bf16x8 vf = *(const bf16x8*)((const char*)&Vl[cur][0] + vb);
        o_acc[nd] = mfma_bf16(pf, vf, o_acc[nd]);
      }
    }
    __builtin_amdgcn_s_setprio(0);
    __syncthreads();  // drains vmcnt(0): next tile staged; all reads of cur done
  }

  // ---- epilogue: l for o-row q = lg*4 + r lives at lane l15 = lg*4 + r
#pragma unroll
  for (int r = 0; r < 4; ++r) {
    const float l_r = __shfl(l_l, (lane & 48) | (((lane >> 4) & 3) * 4 + r));
    const float inv = 1.0f / l_r;
    float* orow = Og + (size_t)(qbase + lg * 4 + r) * DHEAD;
#pragma unroll
    for (int nd = 0; nd < 4; ++nd)
      orow[nd * 16 + l15] = o_acc[nd][r] * inv;
  }
#undef STAGE
}

// ---------- fallback (round-1 kernel) if ws_size is too small ----------
__global__ __launch_bounds__(256, 2)
void attn_fb(const float* __restrict__ Qg0, const float* __restrict__ Kg0,
             const float* __restrict__ Vg0, float* __restrict__ Og0) {
  __shared__ __align__(16) bf16 Kl[KB][72];
  __shared__ __align__(16) bf16 Vt[DHEAD][72];
  __shared__ __align__(16) bf16 Pl[4][16][72];
  const int tid = threadIdx.x, wid = tid >> 6, lane = tid & 63;
  const int l15 = lane & 15, lg = lane >> 4;
  const int bh = blockIdx.x >> 5, qb = blockIdx.x & 31;
  const int qbase = qb * 64 + wid * 16;
  const size_t base = (size_t)bh * S_LEN * DHEAD;
  const float* Qg = Qg0 + base;
  const float* Kg = Kg0 + base;
  const float* Vg = Vg0 + base;
  float* Og = Og0 + base;
  const float qscale = 0.125f * 1.44269504088896341f;
  bf16x8 qfrag[2];
  {
    const float* qrow = Qg + (size_t)(qbase + l15) * DHEAD;
#pragma unroll
    for (int h = 0; h < 2; ++h) {
      const float* p = qrow + h * 32 + lg * 8;
      const float4 a = *(const float4*)(p);
      const float4 b = *(const float4*)(p + 4);
      bf16x8 f;
      f[0] = (bf16)(a.x * qscale); f[1] = (bf16)(a.y * qscale);
      f[2] = (bf16)(a.z * qscale); f[3] = (bf16)(a.w * qscale);
      f[4] = (bf16)(b.x * qscale); f[5] = (bf16)(b.y * qscale);
      f[6] = (bf16)(b.z * qscale); f[7] = (bf16)(b.w * qscale);
      qfrag[h] = f;
    }
  }
  float m_r[4], l_r[4];
  f32x4 o_acc[4];
#pragma unroll
  for (int r = 0; r < 4; ++r) {
    m_r[r] = -__builtin_inff();
    l_r[r] = 0.f;
    o_acc[r] = f32x4{0.f, 0.f, 0.f, 0.f};
  }
  for (int kt = 0; kt < NT; ++kt) {
    __syncthreads();
#pragma unroll
    for (int it = 0; it < 4; ++it) {
      const int i = tid + it * 256;
      const int row = i >> 4, c4 = (i & 15) << 2;
      const float4 kk = *(const float4*)(Kg + (size_t)(kt * KB + row) * DHEAD + c4);
      bf16x4 kb;
      kb[0] = (bf16)kk.x; kb[1] = (bf16)kk.y; kb[2] = (bf16)kk.z; kb[3] = (bf16)kk.w;
      *(bf16x4*)&Kl[row][c4] = kb;
      const float4 vv = *(const float4*)(Vg + (size_t)(kt * KB + row) * DHEAD + c4);
      Vt[c4 + 0][row] = (bf16)vv.x;
      Vt[c4 + 1][row] = (bf16)vv.y;
      Vt[c4 + 2][row] = (bf16)vv.z;
      Vt[c4 + 3][row] = (bf16)vv.w;
    }
    __syncthreads();
    f32x4 sacc[4] = {};
#pragma unroll
    for (int ns = 0; ns < 4; ++ns)
#pragma unroll
      for (int h = 0; h < 2; ++h) {
        const bf16x8 kf = *(const bf16x8*)&Kl[ns * 16 + l15][h * 32 + lg * 8];
        sacc[ns] = mfma_bf16(qfrag[h], kf, sacc[ns]);
      }
    float rmax[4], alpha[4], rsum[4];
#pragma unroll
    for (int r = 0; r < 4; ++r)
      rmax[r] = fmaxf(fmaxf(sacc[0][r], sacc[1][r]), fmaxf(sacc[2][r], sacc[3][r]));
#pragma unroll
    for (int off = 1; off < 16; off <<= 1)
#pragma unroll
      for (int r = 0; r < 4; ++r)
        rmax[r] = fmaxf(rmax[r], __shfl_xor(rmax[r], off));
#pragma unroll
    for (int r = 0; r < 4; ++r) {
      const float mn = fmaxf(m_r[r], rmax[r]);
      alpha[r] = exp2f(m_r[r] - mn);
      m_r[r] = mn;
      rsum[r] = 0.f;
    }
#pragma unroll
    for (int ns = 0; ns < 4; ++ns)
#pragma unroll
      for (int r = 0; r < 4; ++r) {
        const float p = exp2f(sacc[ns][r] - m_r[r]);
        sacc[ns][r] = p;
        rsum[r] += p;
      }
#pragma unroll
    for (int off = 1; off < 16; off <<= 1)
#pragma unroll
      for (int r = 0; r < 4; ++r)
        rsum[r] += __shfl_xor(rsum[r], off);
#pragma unroll
    for (int r = 0; r < 4; ++r) {
      l_r[r] = l_r[r] * alpha[r] + rsum[r];
      o_acc[0][r] *= alpha[r];
      o_acc[1][r] *= alpha[r];
      o_acc[2][r] *= alpha[r];
      o_acc[3][r] *= alpha[r];
    }
#pragma unroll
    for (int ns = 0; ns < 4; ++ns)
#pragma unroll
      for (int r = 0; r < 4; ++r)
        Pl[wid][lg * 4 + r][ns * 16 + l15] = (bf16)sacc[ns][r];
    asm volatile("s_waitcnt lgkmcnt(0)" ::: "memory");
#pragma unroll
    for (int h = 0; h < 2; ++h) {
      const bf16x8 pf = *(const bf16x8*)&Pl[wid][l15][h * 32 + lg * 8];
#pragma unroll
      for (int nd = 0; nd < 4; ++nd) {
        const bf16x8 vf = *(const bf16x8*)&Vt[nd * 16 + l15][h * 32 + lg * 8];
        o_acc[nd] = mfma_bf16(pf, vf, o_acc[nd]);
      }
    }
  }
#pragma unroll
  for (int r = 0; r < 4; ++r) {
    const float inv = 1.0f / l_r[r];
    float* orow = Og + (size_t)(qbase + lg * 4 + r) * DHEAD;
#pragma unroll
    for (int nd = 0; nd < 4; ++nd)
      orow[nd * 16 + l15] = o_acc[nd][r] * inv;
  }
}

extern "C" void kernel_launch(void* const* d_in, const int* in_sizes, int n_in,
                              void* d_out, int out_size, void* d_ws, size_t ws_size,
                              hipStream_t stream) {
  const float* Q = (const float*)d_in[0];
  const float* K = (const float*)d_in[1];
  const float* V = (const float*)d_in[2];
  float* O = (float*)d_out;

  const size_t elems = (size_t)BH * S_LEN * DHEAD;   // 4,194,304
  const size_t bf16_bytes = elems * 2;               // 8,388,608
  if (ws_size >= 2 * bf16_bytes) {
    bf16* Kb = (bf16*)d_ws;
    bf16* Vt = (bf16*)((char*)d_ws + bf16_bytes);
    hipLaunchKernelGGL(kv_prep, dim3(BH * 32), dim3(256), 0, stream, K, V, Kb, Vt);
    hipLaunchKernelGGL(attn_fwd4, dim3(BH * (S_LEN / QB)), dim3(512), 0, stream,
                       Q, Kb, Vt, O);
  } else {
    hipLaunchKernelGGL(attn_fb, dim3(1024), dim3(256), 0, stream, Q, K, V, O);
  }
}

// Round 11
// 141.897 us; speedup vs baseline: 1.8194x; 1.0068x over previous
//
#include <hip/hip_runtime.h>

typedef __bf16 bf16;
typedef __bf16 bf16x4 __attribute__((ext_vector_type(4)));
typedef __bf16 bf16x8 __attribute__((ext_vector_type(8)));
typedef float  f32x4  __attribute__((ext_vector_type(4)));

#define S_LEN 2048
#define DHEAD 64
#define BH    32
#define QB    128              // q rows per block: 4 waves x 32 rows
#define KB    64               // kv rows per tile
#define NT    (S_LEN / KB)     // 32 kv tiles

static __device__ __forceinline__ void async_cp16(const bf16* g, bf16* l) {
  __builtin_amdgcn_global_load_lds(
      (const __attribute__((address_space(1))) void*)g,
      (__attribute__((address_space(3))) void*)l, 16, 0, 0);
}

static __device__ __forceinline__ f32x4 mfma_bf16(bf16x8 a, bf16x8 b, f32x4 c) {
  return __builtin_amdgcn_mfma_f32_16x16x32_bf16(a, b, c, 0, 0, 0);
}

// ---------- pre-pass: K fp32->bf16 copy + V fp32->bf16 transpose, per tile ----
__global__ __launch_bounds__(256)
void kv_prep(const float* __restrict__ K, const float* __restrict__ V,
             bf16* __restrict__ Kb, bf16* __restrict__ Vt) {
  __shared__ bf16 t[64][72];
  const int bh = blockIdx.x >> 5;     // 0..31
  const int kt = blockIdx.x & 31;     // kv tile
  const int tid = threadIdx.x;
  const size_t tbase = ((size_t)bh * S_LEN + kt * 64) * DHEAD;

  // K: straight convert, 64x64 tile = 512 chunks of 8 floats
  const float* ksrc = K + tbase;
  bf16* kdst = Kb + tbase;
#pragma unroll
  for (int it = 0; it < 2; ++it) {
    const int i = tid + it * 256;       // 0..511
    const float4 a = ((const float4*)ksrc)[2 * i];
    const float4 b = ((const float4*)ksrc)[2 * i + 1];
    bf16x8 o;
    o[0] = (bf16)a.x; o[1] = (bf16)a.y; o[2] = (bf16)a.z; o[3] = (bf16)a.w;
    o[4] = (bf16)b.x; o[5] = (bf16)b.y; o[6] = (bf16)b.z; o[7] = (bf16)b.w;
    ((bf16x8*)kdst)[i] = o;
  }

  // V: transpose to [bh][d][S]
  const float* vsrc = V + tbase;
  bf16* vdst = Vt + (size_t)bh * DHEAD * S_LEN + kt * 64;
#pragma unroll
  for (int it = 0; it < 4; ++it) {
    const int i = tid + it * 256;       // 1024 float4 chunks
    const int r = i >> 4, c4 = (i & 15) << 2;
    const float4 v = *(const float4*)(vsrc + (size_t)r * DHEAD + c4);
    bf16x4 o;
    o[0] = (bf16)v.x; o[1] = (bf16)v.y; o[2] = (bf16)v.z; o[3] = (bf16)v.w;
    *(bf16x4*)&t[r][c4] = o;
  }
  __syncthreads();
#pragma unroll
  for (int it = 0; it < 2; ++it) {
    const int j = tid + it * 256;       // 512 out-chunks of 8
    const int d = j >> 3, c8 = (j & 7) << 3;
    bf16x8 o;
#pragma unroll
    for (int e = 0; e < 8; ++e) o[e] = t[c8 + e][d];
    *(bf16x8*)(vdst + (size_t)d * S_LEN + c8) = o;
  }
}

// ---------- main: flash attention; 4 waves x 32 q-rows; swapped QK^T;
// per-lane softmax with deferred l-reduction (no common-path cross-lane ops) ----
__global__ __launch_bounds__(256, 2)
void attn_fwd5(const float* __restrict__ Qg0, const bf16* __restrict__ Kb0,
               const bf16* __restrict__ Vt0, float* __restrict__ Og0) {
  __shared__ __align__(16) bf16 Kl[2][KB * DHEAD];   // [kv 64][d 64], xor-swizzled
  __shared__ __align__(16) bf16 Vl[2][DHEAD * KB];   // [d 64][kv 64], xor-swizzled
  __shared__ __align__(16) bf16 Pl[4][32][64];       // per-wave P, xor-swizzled

  const int tid = threadIdx.x, wid = tid >> 6, lane = tid & 63;
  const int l15 = lane & 15, lg = lane >> 4;
  const int bh = blockIdx.x >> 4;       // 0..31
  const int qb = blockIdx.x & 15;       // 0..15
  const int qbase = qb * QB + wid * 32;

  const float* Qg = Qg0 + (size_t)bh * S_LEN * DHEAD;
  const bf16* Kb = Kb0 + (size_t)bh * S_LEN * DHEAD;
  const bf16* Vt = Vt0 + (size_t)bh * DHEAD * S_LEN;
  float* Og = Og0 + (size_t)bh * S_LEN * DHEAD;

  // staging: linear LDS dest; global source chunk inverse-swizzled (rule #21)
  const int srow = wid * 8 + (lane >> 3);           // 0..31
  const int scl = ((lane & 7) ^ (srow & 7)) << 3;   // element offset in row
  const bf16* kg0 = Kb + (size_t)srow * DHEAD + scl;
  const bf16* vg0 = Vt + (size_t)srow * S_LEN + scl;

#define STAGE(b, t)                                                  \
  do {                                                               \
    const bf16* kg_ = kg0 + (size_t)(t) * KB * DHEAD;                \
    const bf16* vg_ = vg0 + (t) * KB;                                \
    async_cp16(kg_, &Kl[b][wid * 512]);                              \
    async_cp16(kg_ + 32 * DHEAD, &Kl[b][2048 + wid * 512]);          \
    async_cp16(vg_, &Vl[b][wid * 512]);                              \
    async_cp16(vg_ + (size_t)32 * S_LEN, &Vl[b][2048 + wid * 512]);  \
  } while (0)

  // ---- Q fragments: lane l15 -> q-row (B-operand col); 2 q-subtiles (rs)
  const float qscale = 0.125f * 1.44269504088896341f;
  bf16x8 qfrag[2][2];
#pragma unroll
  for (int rs = 0; rs < 2; ++rs) {
    const float* qrow = Qg + (size_t)(qbase + rs * 16 + l15) * DHEAD;
#pragma unroll
    for (int h = 0; h < 2; ++h) {
      const float* p = qrow + h * 32 + lg * 8;
      const float4 a = *(const float4*)(p);
      const float4 b = *(const float4*)(p + 4);
      bf16x8 f;
      f[0] = (bf16)(a.x * qscale); f[1] = (bf16)(a.y * qscale);
      f[2] = (bf16)(a.z * qscale); f[3] = (bf16)(a.w * qscale);
      f[4] = (bf16)(b.x * qscale); f[5] = (bf16)(b.y * qscale);
      f[6] = (bf16)(b.z * qscale); f[7] = (bf16)(b.w * qscale);
      qfrag[rs][h] = f;
    }
  }

  // softmax state: m row-wide (maintained in rescale), l per-lane PARTIAL
  float m_l[2] = {-__builtin_inff(), -__builtin_inff()};
  float l_l[2] = {0.f, 0.f};
  f32x4 o_acc[2][4];
#pragma unroll
  for (int rs = 0; rs < 2; ++rs)
#pragma unroll
    for (int nd = 0; nd < 4; ++nd) o_acc[rs][nd] = f32x4{0.f, 0.f, 0.f, 0.f};

  const int kxor = (l15 & 7) << 4;      // K/V read swizzle: row&7 == l15&7
  const int pswz = (l15 & 7) << 4;      // P swizzle within q-row
  char* pbase0 = (char*)&Pl[wid][0][0] + l15 * 128;
  char* pbase1 = pbase0 + 16 * 128;

  STAGE(0, 0);
  __syncthreads();

  for (int kt = 0; kt < NT; ++kt) {
    const int cur = kt & 1;
    if (kt + 1 < NT) STAGE(cur ^ 1, kt + 1);

    // ---- S^T = K Q^T : lane holds kv = ns*16 + lg*4 + r, q = l15 (per rs)
    f32x4 sacc[2][4] = {};
    __builtin_amdgcn_s_setprio(1);
#pragma unroll
    for (int ns = 0; ns < 4; ++ns) {
      const int krow = ns * 16 + l15;
#pragma unroll
      for (int h = 0; h < 2; ++h) {
        const int kb = krow * 128 + ((((h << 2) + lg) << 4) ^ kxor);
        const bf16x8 kf = *(const bf16x8*)((const char*)&Kl[cur][0] + kb);
        sacc[0][ns] = mfma_bf16(kf, qfrag[0][h], sacc[0][ns]);
        sacc[1][ns] = mfma_bf16(kf, qfrag[1][h], sacc[1][ns]);
      }
    }
    __builtin_amdgcn_s_setprio(0);

    // ---- softmax per q-subtile: common path has NO cross-lane ops
#pragma unroll
    for (int rs = 0; rs < 2; ++rs) {
      float pmax = sacc[rs][0][0];
#pragma unroll
      for (int ns = 0; ns < 4; ++ns)
#pragma unroll
        for (int r = 0; r < 4; ++r) pmax = fmaxf(pmax, sacc[rs][ns][r]);

      // row-wide check via __all on per-lane maxima (equivalent: quantifies
      // over every row's 4 lanes). Rescale branch is rare and wave-uniform.
      if (!__all(pmax <= m_l[rs] + 8.f)) {
        pmax = fmaxf(pmax, __shfl_xor(pmax, 16));
        pmax = fmaxf(pmax, __shfl_xor(pmax, 32));
        const float mn = fmaxf(m_l[rs], pmax);
        const float alpha = __builtin_amdgcn_exp2f(m_l[rs] - mn);  // 1st tile: 0
        m_l[rs] = mn;
        l_l[rs] *= alpha;
#pragma unroll
        for (int r = 0; r < 4; ++r) {
          // alpha for o-row q = lg*4 + r lives at lane with l15 = lg*4 + r
          const float a_r = __shfl(alpha, (lane & 48) | (((lane >> 4) & 3) * 4 + r));
          o_acc[rs][0][r] *= a_r;
          o_acc[rs][1][r] *= a_r;
          o_acc[rs][2][r] *= a_r;
          o_acc[rs][3][r] *= a_r;
        }
      }

      char* pb = rs ? pbase1 : pbase0;
      float rsum = 0.f;
#pragma unroll
      for (int ns = 0; ns < 4; ++ns) {
#pragma unroll
        for (int r = 0; r < 4; ++r) {
          const float p = __builtin_amdgcn_exp2f(sacc[rs][ns][r] - m_l[rs]);
          sacc[rs][ns][r] = p;
          rsum += p;
        }
        bf16x4 pw;
        pw[0] = (bf16)sacc[rs][ns][0]; pw[1] = (bf16)sacc[rs][ns][1];
        pw[2] = (bf16)sacc[rs][ns][2]; pw[3] = (bf16)sacc[rs][ns][3];
        *(bf16x4*)(pb + (((ns << 5) + (lg << 3)) ^ pswz)) = pw;
      }
      l_l[rs] += rsum;   // per-lane partial; cross-lane reduction deferred
    }

    asm volatile("s_waitcnt lgkmcnt(0)" ::: "memory");  // wave-local P wr->rd

    // ---- O += P V : A = P[32q x 64kv] (two 16-row tiles), B = V[64kv x 64d]
    __builtin_amdgcn_s_setprio(1);
#pragma unroll
    for (int h = 0; h < 2; ++h) {
      const int poff = ((h << 6) + (lg << 4)) ^ pswz;
      const bf16x8 pf0 = *(const bf16x8*)(pbase0 + poff);
      const bf16x8 pf1 = *(const bf16x8*)(pbase1 + poff);
#pragma unroll
      for (int nd = 0; nd < 4; ++nd) {
        const int vrow = nd * 16 + l15;
        const int vb = vrow * 128 + ((((h << 2) + lg) << 4) ^ kxor);
        const bf16x8 vf = *(const bf16x8*)((const char*)&Vl[cur][0] + vb);
        o_acc[0][nd] = mfma_bf16(pf0, vf, o_acc[0][nd]);
        o_acc[1][nd] = mfma_bf16(pf1, vf, o_acc[1][nd]);
      }
    }
    __builtin_amdgcn_s_setprio(0);
    __syncthreads();  // next tile staged (issued a full phase ago); reads done
  }

  // ---- epilogue: reduce l partials, redistribute, scale, store
#pragma unroll
  for (int rs = 0; rs < 2; ++rs) {
    l_l[rs] += __shfl_xor(l_l[rs], 16);
    l_l[rs] += __shfl_xor(l_l[rs], 32);   // row-wide l for q = l15
#pragma unroll
    for (int r = 0; r < 4; ++r) {
      const float l_r = __shfl(l_l[rs], (lane & 48) | (((lane >> 4) & 3) * 4 + r));
      const float inv = 1.0f / l_r;
      float* orow = Og + (size_t)(qbase + rs * 16 + lg * 4 + r) * DHEAD;
#pragma unroll
      for (int nd = 0; nd < 4; ++nd)
        orow[nd * 16 + l15] = o_acc[rs][nd][r] * inv;
    }
  }
#undef STAGE
}

// ---------- fallback (round-1 kernel) if ws_size is too small ----------
__global__ __launch_bounds__(256, 2)
void attn_fb(const float* __restrict__ Qg0, const float* __restrict__ Kg0,
             const float* __restrict__ Vg0, float* __restrict__ Og0) {
  __shared__ __align__(16) bf16 Kl[KB][72];
  __shared__ __align__(16) bf16 Vt[DHEAD][72];
  __shared__ __align__(16) bf16 Pl[4][16][72];
  const int tid = threadIdx.x, wid = tid >> 6, lane = tid & 63;
  const int l15 = lane & 15, lg = lane >> 4;
  const int bh = blockIdx.x >> 5, qb = blockIdx.x & 31;
  const int qbase = qb * 64 + wid * 16;
  const size_t base = (size_t)bh * S_LEN * DHEAD;
  const float* Qg = Qg0 + base;
  const float* Kg = Kg0 + base;
  const float* Vg = Vg0 + base;
  float* Og = Og0 + base;
  const float qscale = 0.125f * 1.44269504088896341f;
  bf16x8 qfrag[2];
  {
    const float* qrow = Qg + (size_t)(qbase + l15) * DHEAD;
#pragma unroll
    for (int h = 0; h < 2; ++h) {
      const float* p = qrow + h * 32 + lg * 8;
      const float4 a = *(const float4*)(p);
      const float4 b = *(const float4*)(p + 4);
      bf16x8 f;
      f[0] = (bf16)(a.x * qscale); f[1] = (bf16)(a.y * qscale);
      f[2] = (bf16)(a.z * qscale); f[3] = (bf16)(a.w * qscale);
      f[4] = (bf16)(b.x * qscale); f[5] = (bf16)(b.y * qscale);
      f[6] = (bf16)(b.z * qscale); f[7] = (bf16)(b.w * qscale);
      qfrag[h] = f;
    }
  }
  float m_r[4], l_r[4];
  f32x4 o_acc[4];
#pragma unroll
  for (int r = 0; r < 4; ++r) {
    m_r[r] = -__builtin_inff();
    l_r[r] = 0.f;
    o_acc[r] = f32x4{0.f, 0.f, 0.f, 0.f};
  }
  for (int kt = 0; kt < NT; ++kt) {
    __syncthreads();
#pragma unroll
    for (int it = 0; it < 4; ++it) {
      const int i = tid + it * 256;
      const int row = i >> 4, c4 = (i & 15) << 2;
      const float4 kk = *(const float4*)(Kg + (size_t)(kt * KB + row) * DHEAD + c4);
      bf16x4 kb;
      kb[0] = (bf16)kk.x; kb[1] = (bf16)kk.y; kb[2] = (bf16)kk.z; kb[3] = (bf16)kk.w;
      *(bf16x4*)&Kl[row][c4] = kb;
      const float4 vv = *(const float4*)(Vg + (size_t)(kt * KB + row) * DHEAD + c4);
      Vt[c4 + 0][row] = (bf16)vv.x;
      Vt[c4 + 1][row] = (bf16)vv.y;
      Vt[c4 + 2][row] = (bf16)vv.z;
      Vt[c4 + 3][row] = (bf16)vv.w;
    }
    __syncthreads();
    f32x4 sacc[4] = {};
#pragma unroll
    for (int ns = 0; ns < 4; ++ns)
#pragma unroll
      for (int h = 0; h < 2; ++h) {
        const bf16x8 kf = *(const bf16x8*)&Kl[ns * 16 + l15][h * 32 + lg * 8];
        sacc[ns] = mfma_bf16(qfrag[h], kf, sacc[ns]);
      }
    float rmax[4], alpha[4], rsum[4];
#pragma unroll
    for (int r = 0; r < 4; ++r)
      rmax[r] = fmaxf(fmaxf(sacc[0][r], sacc[1][r]), fmaxf(sacc[2][r], sacc[3][r]));
#pragma unroll
    for (int off = 1; off < 16; off <<= 1)
#pragma unroll
      for (int r = 0; r < 4; ++r)
        rmax[r] = fmaxf(rmax[r], __shfl_xor(rmax[r], off));
#pragma unroll
    for (int r = 0; r < 4; ++r) {
      const float mn = fmaxf(m_r[r], rmax[r]);
      alpha[r] = exp2f(m_r[r] - mn);
      m_r[r] = mn;
      rsum[r] = 0.f;
    }
#pragma unroll
    for (int ns = 0; ns < 4; ++ns)
#pragma unroll
      for (int r = 0; r < 4; ++r) {
        const float p = exp2f(sacc[ns][r] - m_r[r]);
        sacc[ns][r] = p;
        rsum[r] += p;
      }
#pragma unroll
    for (int off = 1; off < 16; off <<= 1)
#pragma unroll
      for (int r = 0; r < 4; ++r)
        rsum[r] += __shfl_xor(rsum[r], off);
#pragma unroll
    for (int r = 0; r < 4; ++r) {
      l_r[r] = l_r[r] * alpha[r] + rsum[r];
      o_acc[0][r] *= alpha[r];
      o_acc[1][r] *= alpha[r];
      o_acc[2][r] *= alpha[r];
      o_acc[3][r] *= alpha[r];
    }
#pragma unroll
    for (int ns = 0; ns < 4; ++ns)
#pragma unroll
      for (int r = 0; r < 4; ++r)
        Pl[wid][lg * 4 + r][ns * 16 + l15] = (bf16)sacc[ns][r];
    asm volatile("s_waitcnt lgkmcnt(0)" ::: "memory");
#pragma unroll
    for (int h = 0; h < 2; ++h) {
      const bf16x8 pf = *(const bf16x8*)&Pl[wid][l15][h * 32 + lg * 8];
#pragma unroll
      for (int nd = 0; nd < 4; ++nd) {
        const bf16x8 vf = *(const bf16x8*)&Vt[nd * 16 + l15][h * 32 + lg * 8];
        o_acc[nd] = mfma_bf16(pf, vf, o_acc[nd]);
      }
    }
  }
#pragma unroll
  for (int r = 0; r < 4; ++r) {
    const float inv = 1.0f / l_r[r];
    float* orow = Og + (size_t)(qbase + lg * 4 + r) * DHEAD;
#pragma unroll
    for (int nd = 0; nd < 4; ++nd)
      orow[nd * 16 + l15] = o_acc[nd][r] * inv;
  }
}

extern "C" void kernel_launch(void* const* d_in, const int* in_sizes, int n_in,
                              void* d_out, int out_size, void* d_ws, size_t ws_size,
                              hipStream_t stream) {
  const float* Q = (const float*)d_in[0];
  const float* K = (const float*)d_in[1];
  const float* V = (const float*)d_in[2];
  float* O = (float*)d_out;

  const size_t elems = (size_t)BH * S_LEN * DHEAD;   // 4,194,304
  const size_t bf16_bytes = elems * 2;               // 8,388,608
  if (ws_size >= 2 * bf16_bytes) {
    bf16* Kb = (bf16*)d_ws;
    bf16* Vt = (bf16*)((char*)d_ws + bf16_bytes);
    hipLaunchKernelGGL(kv_prep, dim3(BH * 32), dim3(256), 0, stream, K, V, Kb, Vt);
    hipLaunchKernelGGL(attn_fwd5, dim3(BH * (S_LEN / QB)), dim3(256), 0, stream,
                       Q, Kb, Vt, O);
  } else {
    hipLaunchKernelGGL(attn_fb, dim3(1024), dim3(256), 0, stream, Q, K, V, O);
  }
}

// Round 12
// 135.211 us; speedup vs baseline: 1.9093x; 1.0494x over previous
//
#include <hip/hip_runtime.h>

typedef __bf16 bf16;
typedef __bf16 bf16x4 __attribute__((ext_vector_type(4)));
typedef __bf16 bf16x8 __attribute__((ext_vector_type(8)));
typedef float  f32x4  __attribute__((ext_vector_type(4)));

#define S_LEN 2048
#define DHEAD 64
#define BH    32
#define QB    128              // q rows per block: 4 waves x 32 rows
#define KB    64               // kv rows per tile
#define NT    (S_LEN / KB)     // 32 kv tiles

static __device__ __forceinline__ void async_cp16(const bf16* g, bf16* l) {
  __builtin_amdgcn_global_load_lds(
      (const __attribute__((address_space(1))) void*)g,
      (__attribute__((address_space(3))) void*)l, 16, 0, 0);
}

static __device__ __forceinline__ f32x4 mfma_bf16(bf16x8 a, bf16x8 b, f32x4 c) {
  return __builtin_amdgcn_mfma_f32_16x16x32_bf16(a, b, c, 0, 0, 0);
}

// ---------- pre-pass: K fp32->bf16 copy + V fp32->bf16 FRAGMENT gather ----
// Vf[bh][kt][nd][h][lane][j] = V[bh][kt*64 + 32h + 16(j>>2) + 4(lane>>4) + (j&3)]
//                               [nd*16 + (lane&15)]
// so the main kernel's vf load for (h,nd) is one contiguous 1KB b128 per wave.
__global__ __launch_bounds__(256)
void kv_prep2(const float* __restrict__ K, const float* __restrict__ V,
              bf16* __restrict__ Kb, bf16* __restrict__ Vf) {
  __shared__ bf16 t[64][72];
  const int bh = blockIdx.x >> 5;     // 0..31
  const int kt = blockIdx.x & 31;     // kv tile
  const int tid = threadIdx.x;
  const size_t tbase = ((size_t)bh * S_LEN + kt * 64) * DHEAD;

  // K: straight convert, 64x64 tile
  const float* ksrc = K + tbase;
  bf16* kdst = Kb + tbase;
#pragma unroll
  for (int it = 0; it < 2; ++it) {
    const int i = tid + it * 256;       // 0..511
    const float4 a = ((const float4*)ksrc)[2 * i];
    const float4 b = ((const float4*)ksrc)[2 * i + 1];
    bf16x8 o;
    o[0] = (bf16)a.x; o[1] = (bf16)a.y; o[2] = (bf16)a.z; o[3] = (bf16)a.w;
    o[4] = (bf16)b.x; o[5] = (bf16)b.y; o[6] = (bf16)b.z; o[7] = (bf16)b.w;
    ((bf16x8*)kdst)[i] = o;
  }

  // V: stage bf16 tile [row][d] to LDS
  const float* vsrc = V + tbase;
#pragma unroll
  for (int it = 0; it < 4; ++it) {
    const int i = tid + it * 256;       // 1024 float4 chunks
    const int r = i >> 4, c4 = (i & 15) << 2;
    const float4 v = *(const float4*)(vsrc + (size_t)r * DHEAD + c4);
    bf16x4 o;
    o[0] = (bf16)v.x; o[1] = (bf16)v.y; o[2] = (bf16)v.z; o[3] = (bf16)v.w;
    *(bf16x4*)&t[r][c4] = o;
  }
  __syncthreads();

  // gather to fragment layout (8 KB per (bh,kt))
  bf16* vdst = Vf + (size_t)bh * S_LEN * DHEAD + (size_t)kt * 4096;
  const int lane = tid & 63, nd = tid >> 6;
  const int lg = lane >> 4, l15 = lane & 15;
#pragma unroll
  for (int h = 0; h < 2; ++h) {
    bf16x8 o;
#pragma unroll
    for (int j = 0; j < 8; ++j)
      o[j] = t[32 * h + 16 * (j >> 2) + 4 * lg + (j & 3)][nd * 16 + l15];
    *(bf16x8*)(vdst + ((nd * 2 + h) * 64 + lane) * 8) = o;
  }
}

// ---------- main: flash attention; P never leaves registers (k-slot remap);
// V frags from global/L2; K staged in LDS; no P fence; XCD-swizzled blocks ----
__global__ __launch_bounds__(256, 2)
void attn_fwd6(const float* __restrict__ Qg0, const bf16* __restrict__ Kb0,
               const bf16* __restrict__ Vf0, float* __restrict__ Og0) {
  __shared__ __align__(16) bf16 Kl[2][KB * DHEAD];   // 16 KB, xor-swizzled

  const int tid = threadIdx.x, wid = tid >> 6, lane = tid & 63;
  const int l15 = lane & 15, lg = lane >> 4;
  const int bid = blockIdx.x;
  const int swz = ((bid & 7) << 6) | (bid >> 3);   // XCD-contiguous (512%8==0)
  const int bh = swz >> 4;              // 0..31
  const int qb = swz & 15;              // 0..15
  const int qbase = qb * QB + wid * 32;

  const float* Qg = Qg0 + (size_t)bh * S_LEN * DHEAD;
  const bf16* Kb = Kb0 + (size_t)bh * S_LEN * DHEAD;
  const bf16* Vf = Vf0 + (size_t)bh * S_LEN * DHEAD;
  float* Og = Og0 + (size_t)bh * S_LEN * DHEAD;

  // K staging: linear LDS dest; global source chunk inverse-swizzled (rule #21)
  const int srow = wid * 8 + (lane >> 3);           // 0..31
  const int scl = ((lane & 7) ^ (srow & 7)) << 3;   // element offset in row
  const bf16* kg0 = Kb + (size_t)srow * DHEAD + scl;

#define STAGE(b, t)                                            \
  do {                                                         \
    const bf16* kg_ = kg0 + (size_t)(t) * KB * DHEAD;          \
    async_cp16(kg_, &Kl[b][wid * 512]);                        \
    async_cp16(kg_ + 32 * DHEAD, &Kl[b][2048 + wid * 512]);    \
  } while (0)

  // ---- Q fragments: lane l15 -> q-row (B-operand col); 2 q-subtiles (rs)
  const float qscale = 0.125f * 1.44269504088896341f;
  bf16x8 qfrag[2][2];
#pragma unroll
  for (int rs = 0; rs < 2; ++rs) {
    const float* qrow = Qg + (size_t)(qbase + rs * 16 + l15) * DHEAD;
#pragma unroll
    for (int h = 0; h < 2; ++h) {
      const float* p = qrow + h * 32 + lg * 8;
      const float4 a = *(const float4*)(p);
      const float4 b = *(const float4*)(p + 4);
      bf16x8 f;
      f[0] = (bf16)(a.x * qscale); f[1] = (bf16)(a.y * qscale);
      f[2] = (bf16)(a.z * qscale); f[3] = (bf16)(a.w * qscale);
      f[4] = (bf16)(b.x * qscale); f[5] = (bf16)(b.y * qscale);
      f[6] = (bf16)(b.z * qscale); f[7] = (bf16)(b.w * qscale);
      qfrag[rs][h] = f;
    }
  }

  float m_l[2] = {-__builtin_inff(), -__builtin_inff()};
  float l_l[2] = {0.f, 0.f};
  f32x4 o_acc[2][4];
#pragma unroll
  for (int rs = 0; rs < 2; ++rs)
#pragma unroll
    for (int nd = 0; nd < 4; ++nd) o_acc[rs][nd] = f32x4{0.f, 0.f, 0.f, 0.f};

  const int kxor = (l15 & 7) << 4;      // K read swizzle: row&7 == l15&7
  const bf16* vlane = Vf + lane * 8;    // per-lane V-frag base

  STAGE(0, 0);
  __syncthreads();

  for (int kt = 0; kt < NT; ++kt) {
    const int cur = kt & 1;
    if (kt + 1 < NT) STAGE(cur ^ 1, kt + 1);

    // ---- V fragment loads for THIS tile (global/L2, coalesced 1KB each);
    // issued early, consumed after softmax: ~600 cyc of latency slack
    bf16x8 vf[2][4];
    {
      const bf16* vb = vlane + (size_t)kt * 4096;
#pragma unroll
      for (int nd = 0; nd < 4; ++nd)
#pragma unroll
        for (int h = 0; h < 2; ++h)
          vf[h][nd] = *(const bf16x8*)(vb + (nd * 2 + h) * 512);
    }

    // ---- S^T = K Q^T : lane holds kv = ns*16 + lg*4 + r, q = l15 (per rs)
    f32x4 sacc[2][4] = {};
    __builtin_amdgcn_s_setprio(1);
#pragma unroll
    for (int ns = 0; ns < 4; ++ns) {
      const int krow = ns * 16 + l15;
#pragma unroll
      for (int h = 0; h < 2; ++h) {
        const int kb = krow * 128 + ((((h << 2) + lg) << 4) ^ kxor);
        const bf16x8 kf = *(const bf16x8*)((const char*)&Kl[cur][0] + kb);
        sacc[0][ns] = mfma_bf16(kf, qfrag[0][h], sacc[0][ns]);
        sacc[1][ns] = mfma_bf16(kf, qfrag[1][h], sacc[1][ns]);
      }
    }
    __builtin_amdgcn_s_setprio(0);

    // ---- softmax per q-subtile; P packed in-register (no LDS, no fence)
    bf16x8 pa[2][2];
#pragma unroll
    for (int rs = 0; rs < 2; ++rs) {
      float pmax = sacc[rs][0][0];
#pragma unroll
      for (int ns = 0; ns < 4; ++ns)
#pragma unroll
        for (int r = 0; r < 4; ++r) pmax = fmaxf(pmax, sacc[rs][ns][r]);

      if (!__all(pmax <= m_l[rs] + 8.f)) {       // rare, wave-uniform
        pmax = fmaxf(pmax, __shfl_xor(pmax, 16));
        pmax = fmaxf(pmax, __shfl_xor(pmax, 32));
        const float mn = fmaxf(m_l[rs], pmax);
        const float alpha = __builtin_amdgcn_exp2f(m_l[rs] - mn);  // 1st tile: 0
        m_l[rs] = mn;
        l_l[rs] *= alpha;
#pragma unroll
        for (int r = 0; r < 4; ++r) {
          const float a_r = __shfl(alpha, (lane & 48) | (((lane >> 4) & 3) * 4 + r));
          o_acc[rs][0][r] *= a_r;
          o_acc[rs][1][r] *= a_r;
          o_acc[rs][2][r] *= a_r;
          o_acc[rs][3][r] *= a_r;
        }
      }

      float rsum = 0.f;
#pragma unroll
      for (int ns = 0; ns < 4; ++ns)
#pragma unroll
        for (int r = 0; r < 4; ++r) {
          const float p = __builtin_amdgcn_exp2f(sacc[rs][ns][r] - m_l[rs]);
          sacc[rs][ns][r] = p;
          rsum += p;
        }
      l_l[rs] += rsum;   // per-lane partial; reduced once in epilogue

      // pack P: k-slot (h,lg,j) == kv 32h+16(j>>2)+4lg+(j&3) -> lane-local regs
      bf16x8 w0, w1;
#pragma unroll
      for (int r = 0; r < 4; ++r) {
        w0[r]     = (bf16)sacc[rs][0][r];
        w0[r + 4] = (bf16)sacc[rs][1][r];
        w1[r]     = (bf16)sacc[rs][2][r];
        w1[r + 4] = (bf16)sacc[rs][3][r];
      }
      pa[rs][0] = w0;
      pa[rs][1] = w1;
    }

    // ---- O += P V : pure register dataflow (Vf uses the same k-slot map)
    __builtin_amdgcn_s_setprio(1);
#pragma unroll
    for (int h = 0; h < 2; ++h)
#pragma unroll
      for (int nd = 0; nd < 4; ++nd) {
        o_acc[0][nd] = mfma_bf16(pa[0][h], vf[h][nd], o_acc[0][nd]);
        o_acc[1][nd] = mfma_bf16(pa[1][h], vf[h][nd], o_acc[1][nd]);
      }
    __builtin_amdgcn_s_setprio(0);
    __syncthreads();  // K dbuf: next tile staged; all Kl[cur] reads done
  }

  // ---- epilogue: reduce l partials, redistribute, scale, store
#pragma unroll
  for (int rs = 0; rs < 2; ++rs) {
    l_l[rs] += __shfl_xor(l_l[rs], 16);
    l_l[rs] += __shfl_xor(l_l[rs], 32);   // row-wide l for q = l15
#pragma unroll
    for (int r = 0; r < 4; ++r) {
      const float l_r = __shfl(l_l[rs], (lane & 48) | (((lane >> 4) & 3) * 4 + r));
      const float inv = 1.0f / l_r;
      float* orow = Og + (size_t)(qbase + rs * 16 + lg * 4 + r) * DHEAD;
#pragma unroll
      for (int nd = 0; nd < 4; ++nd)
        orow[nd * 16 + l15] = o_acc[rs][nd][r] * inv;
    }
  }
#undef STAGE
}

// ---------- fallback (round-1 kernel) if ws_size is too small ----------
__global__ __launch_bounds__(256, 2)
void attn_fb(const float* __restrict__ Qg0, const float* __restrict__ Kg0,
             const float* __restrict__ Vg0, float* __restrict__ Og0) {
  __shared__ __align__(16) bf16 Kl[KB][72];
  __shared__ __align__(16) bf16 Vt[DHEAD][72];
  __shared__ __align__(16) bf16 Pl[4][16][72];
  const int tid = threadIdx.x, wid = tid >> 6, lane = tid & 63;
  const int l15 = lane & 15, lg = lane >> 4;
  const int bh = blockIdx.x >> 5, qb = blockIdx.x & 31;
  const int qbase = qb * 64 + wid * 16;
  const size_t base = (size_t)bh * S_LEN * DHEAD;
  const float* Qg = Qg0 + base;
  const float* Kg = Kg0 + base;
  const float* Vg = Vg0 + base;
  float* Og = Og0 + base;
  const float qscale = 0.125f * 1.44269504088896341f;
  bf16x8 qfrag[2];
  {
    const float* qrow = Qg + (size_t)(qbase + l15) * DHEAD;
#pragma unroll
    for (int h = 0; h < 2; ++h) {
      const float* p = qrow + h * 32 + lg * 8;
      const float4 a = *(const float4*)(p);
      const float4 b = *(const float4*)(p + 4);
      bf16x8 f;
      f[0] = (bf16)(a.x * qscale); f[1] = (bf16)(a.y * qscale);
      f[2] = (bf16)(a.z * qscale); f[3] = (bf16)(a.w * qscale);
      f[4] = (bf16)(b.x * qscale); f[5] = (bf16)(b.y * qscale);
      f[6] = (bf16)(b.z * qscale); f[7] = (bf16)(b.w * qscale);
      qfrag[h] = f;
    }
  }
  float m_r[4], l_r[4];
  f32x4 o_acc[4];
#pragma unroll
  for (int r = 0; r < 4; ++r) {
    m_r[r] = -__builtin_inff();
    l_r[r] = 0.f;
    o_acc[r] = f32x4{0.f, 0.f, 0.f, 0.f};
  }
  for (int kt = 0; kt < NT; ++kt) {
    __syncthreads();
#pragma unroll
    for (int it = 0; it < 4; ++it) {
      const int i = tid + it * 256;
      const int row = i >> 4, c4 = (i & 15) << 2;
      const float4 kk = *(const float4*)(Kg + (size_t)(kt * KB + row) * DHEAD + c4);
      bf16x4 kb;
      kb[0] = (bf16)kk.x; kb[1] = (bf16)kk.y; kb[2] = (bf16)kk.z; kb[3] = (bf16)kk.w;
      *(bf16x4*)&Kl[row][c4] = kb;
      const float4 vv = *(const float4*)(Vg + (size_t)(kt * KB + row) * DHEAD + c4);
      Vt[c4 + 0][row] = (bf16)vv.x;
      Vt[c4 + 1][row] = (bf16)vv.y;
      Vt[c4 + 2][row] = (bf16)vv.z;
      Vt[c4 + 3][row] = (bf16)vv.w;
    }
    __syncthreads();
    f32x4 sacc[4] = {};
#pragma unroll
    for (int ns = 0; ns < 4; ++ns)
#pragma unroll
      for (int h = 0; h < 2; ++h) {
        const bf16x8 kf = *(const bf16x8*)&Kl[ns * 16 + l15][h * 32 + lg * 8];
        sacc[ns] = mfma_bf16(qfrag[h], kf, sacc[ns]);
      }
    float rmax[4], alpha[4], rsum[4];
#pragma unroll
    for (int r = 0; r < 4; ++r)
      rmax[r] = fmaxf(fmaxf(sacc[0][r], sacc[1][r]), fmaxf(sacc[2][r], sacc[3][r]));
#pragma unroll
    for (int off = 1; off < 16; off <<= 1)
#pragma unroll
      for (int r = 0; r < 4; ++r)
        rmax[r] = fmaxf(rmax[r], __shfl_xor(rmax[r], off));
#pragma unroll
    for (int r = 0; r < 4; ++r) {
      const float mn = fmaxf(m_r[r], rmax[r]);
      alpha[r] = exp2f(m_r[r] - mn);
      m_r[r] = mn;
      rsum[r] = 0.f;
    }
#pragma unroll
    for (int ns = 0; ns < 4; ++ns)
#pragma unroll
      for (int r = 0; r < 4; ++r) {
        const float p = exp2f(sacc[ns][r] - m_r[r]);
        sacc[ns][r] = p;
        rsum[r] += p;
      }
#pragma unroll
    for (int off = 1; off < 16; off <<= 1)
#pragma unroll
      for (int r = 0; r < 4; ++r)
        rsum[r] += __shfl_xor(rsum[r], off);
#pragma unroll
    for (int r = 0; r < 4; ++r) {
      l_r[r] = l_r[r] * alpha[r] + rsum[r];
      o_acc[0][r] *= alpha[r];
      o_acc[1][r] *= alpha[r];
      o_acc[2][r] *= alpha[r];
      o_acc[3][r] *= alpha[r];
    }
#pragma unroll
    for (int ns = 0; ns < 4; ++ns)
#pragma unroll
      for (int r = 0; r < 4; ++r)
        Pl[wid][lg * 4 + r][ns * 16 + l15] = (bf16)sacc[ns][r];
    asm volatile("s_waitcnt lgkmcnt(0)" ::: "memory");
#pragma unroll
    for (int h = 0; h < 2; ++h) {
      const bf16x8 pf = *(const bf16x8*)&Pl[wid][l15][h * 32 + lg * 8];
#pragma unroll
      for (int nd = 0; nd < 4; ++nd) {
        const bf16x8 vf = *(const bf16x8*)&Vt[nd * 16 + l15][h * 32 + lg * 8];
        o_acc[nd] = mfma_bf16(pf, vf, o_acc[nd]);
      }
    }
  }
#pragma unroll
  for (int r = 0; r < 4; ++r) {
    const float inv = 1.0f / l_r[r];
    float* orow = Og + (size_t)(qbase + lg * 4 + r) * DHEAD;
#pragma unroll
    for (int nd = 0; nd < 4; ++nd)
      orow[nd * 16 + l15] = o_acc[nd][r] * inv;
  }
}

extern "C" void kernel_launch(void* const* d_in, const int* in_sizes, int n_in,
                              void* d_out, int out_size, void* d_ws, size_t ws_size,
                              hipStream_t stream) {
  const float* Q = (const float*)d_in[0];
  const float* K = (const float*)d_in[1];
  const float* V = (const float*)d_in[2];
  float* O = (float*)d_out;

  const size_t elems = (size_t)BH * S_LEN * DHEAD;   // 4,194,304
  const size_t bf16_bytes = elems * 2;               // 8,388,608
  if (ws_size >= 2 * bf16_bytes) {
    bf16* Kb = (bf16*)d_ws;
    bf16* Vf = (bf16*)((char*)d_ws + bf16_bytes);
    hipLaunchKernelGGL(kv_prep2, dim3(BH * 32), dim3(256), 0, stream, K, V, Kb, Vf);
    hipLaunchKernelGGL(attn_fwd6, dim3(BH * (S_LEN / QB)), dim3(256), 0, stream,
                       Q, Kb, Vf, O);
  } else {
    hipLaunchKernelGGL(attn_fb, dim3(1024), dim3(256), 0, stream, Q, K, V, O);
  }
}